// Round 21
// baseline (671.941 us; speedup 1.0000x reference)
//
#include <hip/hip_runtime.h>

#define NN 50000
#define EE 800000
#define IND 128
#define NCOL 1024
#define KM 320            // K * Mpad = 10*32
#define M30 30
#define RATIO 0.1825741858f   // 30^-0.5
#define EPSF 1e-6f
#define QKSCALE 0.7071067812f // (1/sqrt(0.25)) * 64^-0.25
#define VTS 50176             // vT row stride (196*256)
#define KVSNB 196             // k_kvs node-chunk blocks (256 nodes each)
#define AST 136               // a-tile LDS row stride in bf16 (2-way-free banks)

typedef __attribute__((ext_vector_type(8))) short bf16x8;
typedef __attribute__((ext_vector_type(4))) float f32x4;

__device__ __forceinline__ unsigned f2s(float f) {
    unsigned u = __float_as_uint(f);
    return (u & 0x80000000u) ? ~u : (u | 0x80000000u);
}
__device__ __forceinline__ float s2f(unsigned s) {
    return __uint_as_float((s & 0x80000000u) ? (s & 0x7fffffffu) : ~s);
}
__device__ __forceinline__ unsigned short f2bf(float f) {   // RTNE fp32->bf16
    unsigned u = __float_as_uint(f);
    unsigned r = u + 0x7fffu + ((u >> 16) & 1u);
    return (unsigned short)(r >> 16);
}
__device__ __forceinline__ float bf2f(unsigned short h) {
    return __uint_as_float(((unsigned)h) << 16);
}

// ---------- prep: Wt[IND][NCOL] (cols: 0-255 s*Wq^T, 256-511 s*Wk^T, 512-767 Wv^T,
// 768-895 Pq[h,m], 896-1023 Pk[h,m]), bias_ext[NCOL], WoT[256][64]
__global__ void k_prep(const float* __restrict__ Wq, const float* __restrict__ Wqb,
                       const float* __restrict__ Wk, const float* __restrict__ Wkb,
                       const float* __restrict__ Wv, const float* __restrict__ Wvb,
                       const float* __restrict__ Wo, const float* __restrict__ proj,
                       float* __restrict__ Wt, float* __restrict__ bext, float* __restrict__ WoT) {
    int i = blockIdx.x;   // 0..127
    int t = threadIdx.x;  // 0..255
    Wt[i*NCOL + t]       = QKSCALE * Wq[t*IND + i];
    Wt[i*NCOL + 256 + t] = QKSCALE * Wk[t*IND + i];
    Wt[i*NCOL + 512 + t] = Wv[t*IND + i];
    {
        const float* W = (t < 128) ? Wq : Wk;
        int c = (t < 128) ? t : (t - 128);
        int h = c >> 5, m = c & 31;
        float val = 0.f;
        if (m < M30) {
            for (int d = 0; d < 64; ++d)
                val += QKSCALE * W[(h*64+d)*IND + i] * proj[m*64 + d];
        }
        Wt[i*NCOL + 768 + t] = val;
    }
    if (t < 128) {
        int f = i*2 + (t >> 6);
        int o = t & 63;
        WoT[f*64 + o] = Wo[o*256 + f];
    }
    if (i == 0) {
        bext[t]       = QKSCALE * Wqb[t];
        bext[256 + t] = QKSCALE * Wkb[t];
        bext[512 + t] = Wvb[t];
        const float* Bb = (t < 128) ? Wqb : Wkb;
        int c = (t < 128) ? t : (t - 128);
        int h = c >> 5, m = c & 31;
        float val = 0.f;
        if (m < M30) {
            for (int d = 0; d < 64; ++d)
                val += QKSCALE * Bb[h*64+d] * proj[m*64 + d];
        }
        bext[768 + t] = val;
    }
}

// ---------- Wcb: bf16 hi/lo split of Wt, layout [col][k] (MFMA B operand)
__global__ void k_prep2(const float* __restrict__ Wt, unsigned short* __restrict__ Wcb) {
    int idx = blockIdx.x*256 + threadIdx.x;   // 512 blocks -> 131072
    int col = idx >> 7, k = idx & 127;
    float f = Wt[k*NCOL + col];
    unsigned short hi = f2bf(f);
    unsigned short lo = f2bf(f - bf2f(hi));
    Wcb[col*128 + k] = hi;
    Wcb[131072 + col*128 + k] = lo;
}

// ---------- zero vT tail cols [50000,50176) (vT aliases znext; replay determinism)
__global__ void k_ztail(unsigned* __restrict__ vT32) {
    int idx = blockIdx.x*256 + threadIdx.x;  // 88 blocks * 256 = 22528 = 256*88
    int row = idx / 88, c = idx - row*88;
    vT32[(size_t)row * (VTS/2) + (50000/2) + c] = 0u;
}

// ---------- fused QKV+dash GEMM via bf16x2 MFMA (A single-rounded, B hi+lo).
// ROUND-21: back to 128 nodes/block (fastest measured, 137us) and
// __launch_bounds__(256, 1): 1 wave/SIMD allows up to 512 VGPR/lane so
// acc[8][4]=128 + Ah[8] (~230 total) fits WITHOUT spilling (round-19/20 both
// spilled at the 256 cap; latency hiding here is intra-wave: 16 MFMAs/B-pair).
__global__ __launch_bounds__(256, 1) void k_qkv_mfma(const float* __restrict__ z,
                      const unsigned short* __restrict__ Wcb, const float* __restrict__ bext,
                      float* __restrict__ vbuf, float* __restrict__ qp, float* __restrict__ kpb,
                      unsigned* __restrict__ stab) {
    __shared__ __align__(16) unsigned short a_hi[128*AST];
    __shared__ float diag_l[2][4][128];   // [q/k][head][node]
    int t = threadIdx.x;
    int n0 = blockIdx.x * 128;
    int w = t >> 6, lane = t & 63;
    #pragma unroll
    for (int half = 0; half < 2; ++half) {
        int node = (t >> 2) + half*64;
        int ks = (t & 3) * 32;
        bool ok = (n0 + node) < NN;
        const float* zr = z + (size_t)(n0 + node)*IND + ks;
        unsigned hbuf[16];
        #pragma unroll
        for (int c = 0; c < 8; ++c) {
            float4 v = ok ? *(const float4*)(zr + c*4) : make_float4(0.f,0.f,0.f,0.f);
            hbuf[c*2]   = (unsigned)f2bf(v.x) | ((unsigned)f2bf(v.y) << 16);
            hbuf[c*2+1] = (unsigned)f2bf(v.z) | ((unsigned)f2bf(v.w) << 16);
        }
        uint4* hp = (uint4*)(&a_hi[node*AST + ks]);
        #pragma unroll
        for (int c = 0; c < 4; ++c)
            hp[c] = make_uint4(hbuf[c*4], hbuf[c*4+1], hbuf[c*4+2], hbuf[c*4+3]);
    }
    __syncthreads();
    int arow = lane & 15;
    int ao = (lane >> 4) * 8;
    for (int c = 0; c < 4; ++c) {
        int colbase = c*256 + w*64;
        f32x4 acc[8][4];
        #pragma unroll
        for (int mt = 0; mt < 8; ++mt)
            #pragma unroll
            for (int nt = 0; nt < 4; ++nt)
                acc[mt][nt] = (f32x4){0.f,0.f,0.f,0.f};
        #pragma unroll
        for (int ks = 0; ks < 4; ++ks) {
            int ko = ks*32 + ao;
            bf16x8 Ah[8];
            #pragma unroll
            for (int mt = 0; mt < 8; ++mt)
                Ah[mt] = *(const bf16x8*)(&a_hi[(mt*16 + arow)*AST + ko]);
            #pragma unroll
            for (int nt = 0; nt < 4; ++nt) {
                const unsigned short* bp = Wcb + (size_t)(colbase + nt*16 + arow)*128 + ko;
                bf16x8 Bh = *(const bf16x8*)bp;
                bf16x8 Bl = *(const bf16x8*)(bp + 131072);
                #pragma unroll
                for (int mt = 0; mt < 8; ++mt) {
                    acc[mt][nt] = __builtin_amdgcn_mfma_f32_16x16x32_bf16(Ah[mt], Bh, acc[mt][nt], 0, 0, 0);
                    acc[mt][nt] = __builtin_amdgcn_mfma_f32_16x16x32_bf16(Ah[mt], Bl, acc[mt][nt], 0, 0, 0);
                }
            }
        }
        float bv[4];
        #pragma unroll
        for (int nt = 0; nt < 4; ++nt) bv[nt] = bext[colbase + nt*16 + arow];
        #pragma unroll
        for (int mt = 0; mt < 8; ++mt)
            #pragma unroll
            for (int nt = 0; nt < 4; ++nt)
                #pragma unroll
                for (int r = 0; r < 4; ++r)
                    acc[mt][nt][r] += bv[nt];
        if (c < 2) {
            #pragma unroll
            for (int mt = 0; mt < 8; ++mt) {
                #pragma unroll
                for (int r = 0; r < 4; ++r) {
                    float s = 0.f;
                    #pragma unroll
                    for (int nt = 0; nt < 4; ++nt) s += acc[mt][nt][r]*acc[mt][nt][r];
                    s += __shfl_xor(s, 1); s += __shfl_xor(s, 2);
                    s += __shfl_xor(s, 4); s += __shfl_xor(s, 8);
                    if (arow == 0) diag_l[c][w][mt*16 + (lane>>4)*4 + r] = 0.5f*s;
                }
            }
        } else if (c == 2) {
            #pragma unroll
            for (int mt = 0; mt < 8; ++mt)
                #pragma unroll
                for (int r = 0; r < 4; ++r) {
                    int node = n0 + mt*16 + (lane>>4)*4 + r;
                    if (node < NN) {
                        #pragma unroll
                        for (int nt = 0; nt < 4; ++nt)
                            vbuf[(size_t)node*256 + w*64 + nt*16 + arow] = acc[mt][nt][r];
                    }
                }
        } else {
            int hh = (w & 1) * 2;
            if (w < 2) {
                #pragma unroll
                for (int p = 0; p < 2; ++p) {
                    int h = hh + p;
                    #pragma unroll
                    for (int mt = 0; mt < 8; ++mt) {
                        #pragma unroll
                        for (int r = 0; r < 4; ++r) {
                            int row = mt*16 + (lane>>4)*4 + r;
                            float dg = diag_l[0][h][row];
                            float mx = fmaxf(acc[mt][2*p][r],
                                             (arow < 14) ? acc[mt][2*p+1][r] : -3.0e38f);
                            mx = fmaxf(mx, __shfl_xor(mx, 1)); mx = fmaxf(mx, __shfl_xor(mx, 2));
                            mx = fmaxf(mx, __shfl_xor(mx, 4)); mx = fmaxf(mx, __shfl_xor(mx, 8));
                            int node = n0 + row;
                            if (node < NN) {
                                #pragma unroll
                                for (int q2 = 0; q2 < 2; ++q2) {
                                    int m = q2*16 + arow;
                                    float val = 0.f;
                                    if (m < M30)
                                        val = RATIO * (__expf(acc[mt][2*p+q2][r] - dg - mx) + EPSF);
                                    qp[(size_t)node*128 + h*32 + m] = val;
                                }
                            }
                        }
                    }
                }
            } else {
                #pragma unroll
                for (int p = 0; p < 2; ++p) {
                    int h = hh + p;
                    float smax = -3.0e38f;
                    #pragma unroll
                    for (int mt = 0; mt < 8; ++mt) {
                        #pragma unroll
                        for (int r = 0; r < 4; ++r) {
                            int row = mt*16 + (lane>>4)*4 + r;
                            float dg = diag_l[1][h][row];
                            int node = n0 + row;
                            if (node < NN) {
                                #pragma unroll
                                for (int q2 = 0; q2 < 2; ++q2) {
                                    int m = q2*16 + arow;
                                    float d = acc[mt][2*p+q2][r];
                                    bool valid = (m < M30);
                                    kpb[(size_t)node*128 + h*32 + m] = valid ? (d - dg) : 0.f;
                                    if (valid) smax = fmaxf(smax, d);
                                }
                            }
                        }
                    }
                    smax = fmaxf(smax, __shfl_xor(smax, 1));  smax = fmaxf(smax, __shfl_xor(smax, 2));
                    smax = fmaxf(smax, __shfl_xor(smax, 4));  smax = fmaxf(smax, __shfl_xor(smax, 8));
                    smax = fmaxf(smax, __shfl_xor(smax, 16)); smax = fmaxf(smax, __shfl_xor(smax, 32));
                    if (lane == 0) atomicMax(&stab[h], f2s(smax));
                }
            }
        }
        __syncthreads();
    }
}

// ---------- vT[c][n] = bf16(vbuf[n][c]) tiled transpose (64x64 tiles via LDS)
__global__ __launch_bounds__(256) void k_vt(const float* __restrict__ vbuf,
                      unsigned short* __restrict__ vT) {
    __shared__ unsigned short tile[64][72];
    int t = threadIdx.x;
    int n0 = blockIdx.x * 64;
    int c0 = blockIdx.y * 64;
    {
        int node = t >> 2, cs = (t & 3) * 16;
        bool ok = (n0 + node) < NN;
        const float* vr = vbuf + (size_t)(n0 + node)*256 + c0 + cs;
        #pragma unroll
        for (int cc = 0; cc < 4; ++cc) {
            float4 v = ok ? *(const float4*)(vr + cc*4) : make_float4(0.f,0.f,0.f,0.f);
            unsigned u0 = (unsigned)f2bf(v.x) | ((unsigned)f2bf(v.y) << 16);
            unsigned u1 = (unsigned)f2bf(v.z) | ((unsigned)f2bf(v.w) << 16);
            *(unsigned*)(&tile[node][cs + cc*4])     = u0;
            *(unsigned*)(&tile[node][cs + cc*4 + 2]) = u1;
        }
    }
    __syncthreads();
    {
        int d = t >> 2, ns = (t & 3) * 16;
        unsigned ob[8];
        #pragma unroll
        for (int i = 0; i < 8; ++i) {
            unsigned short a = tile[ns + i*2][d];
            unsigned short b = tile[ns + i*2 + 1][d];
            ob[i] = (unsigned)a | ((unsigned)b << 16);
        }
        unsigned short* op = vT + (size_t)(c0 + d)*VTS + n0 + ns;
        *(uint4*)(op)     = make_uint4(ob[0], ob[1], ob[2], ob[3]);
        *(uint4*)(op + 8) = make_uint4(ob[4], ob[5], ob[6], ob[7]);
    }
}

__global__ void k_deg(const int* __restrict__ ei, int* __restrict__ din, int* __restrict__ dout) {
    int e = blockIdx.x*256 + threadIdx.x;
    if (e < EE) {
        atomicAdd(&dout[ei[e]], 1);
        atomicAdd(&din[ei[EE + e]], 1);
    }
}

// ---------- prefix sum over din (3-kernel scan) ----------
__global__ void k_scan_part(const int* __restrict__ din, int* __restrict__ bsum) {
    __shared__ int red[256];
    int t = threadIdx.x;
    int i = blockIdx.x*256 + t;
    red[t] = (i < NN) ? din[i] : 0;
    __syncthreads();
    for (int off = 128; off >= 1; off >>= 1) {
        if (t < off) red[t] += red[t+off];
        __syncthreads();
    }
    if (t == 0) bsum[blockIdx.x] = red[0];
}
__global__ void k_scan_top(const int* __restrict__ bsum, int* __restrict__ boff) {
    if (threadIdx.x == 0) {
        int acc = 0;
        for (int b = 0; b < 196; ++b) { boff[b] = acc; acc += bsum[b]; }
    }
}
// scan finish + rsd = rsqrt(dout) (k_rs folded in)
__global__ void k_scan_fin(const int* __restrict__ din, const int* __restrict__ boff,
                           int* __restrict__ offsets, int* __restrict__ cursor,
                           const int* __restrict__ dout_, float* __restrict__ rsd) {
    __shared__ int s[256];
    int t = threadIdx.x;
    int i = blockIdx.x*256 + t;
    if (i < NN) {
        int d = dout_[i];
        rsd[i] = d > 0 ? rsqrtf((float)d) : 0.f;
    }
    int v = (i < NN) ? din[i] : 0;
    s[t] = v;
    __syncthreads();
    for (int off = 1; off < 256; off <<= 1) {
        int add = (t >= off) ? s[t-off] : 0;
        __syncthreads();
        s[t] += add;
        __syncthreads();
    }
    int excl = s[t] - v + boff[blockIdx.x];
    if (i < NN) { offsets[i] = excl; cursor[i] = excl; }
    if (i == NN-1) offsets[NN] = excl + v;
}

// scatter (row, eid) packed as int2 into CSR-by-col order
__global__ void k_scatter(const int* __restrict__ ei, int* __restrict__ cursor,
                          int2* __restrict__ csr_pack) {
    int e = blockIdx.x*256 + threadIdx.x;
    if (e < EE) {
        int col = ei[EE + e];
        int pos = atomicAdd(&cursor[col], 1);
        csr_pack[pos] = make_int2(ei[e], e);
    }
}

// ---------- finish kp = ratio*(exp(dash-diag-stab)+eps) -> kp_bf (bf16); kp_sum[h][m]
__global__ void k_kp(const float* __restrict__ kpb, const unsigned* __restrict__ stab,
                     float* __restrict__ kp_sum, unsigned short* __restrict__ kp_bf) {
    __shared__ float red[256];
    int t = threadIdx.x;
    int hm = t & 127;
    int h = hm >> 5, m = hm & 31;
    float st = s2f(stab[h]);
    float ksum = 0.f;
    const int total = NN*128;
    for (int idx = blockIdx.x*256 + t; idx < total; idx += gridDim.x*256) {
        float val = kpb[idx];
        float kpv = 0.f;
        if (m < M30) kpv = RATIO * (__expf(val - st) + EPSF);
        kp_bf[idx] = f2bf(kpv);
        ksum += kpv;
    }
    red[t] = ksum;
    __syncthreads();
    if (t < 128) atomicAdd(&kp_sum[hm], red[t] + red[t+128]);
}

// ---------- kvs[h][km][d] = sum_n w[n,km]*v[n,d] via MFMA (16x16x32 bf16).
__global__ __launch_bounds__(256) void k_kvs(const unsigned short* __restrict__ kp_bf,
                      const float* __restrict__ g, const unsigned short* __restrict__ vT,
                      float* __restrict__ kvs, float* __restrict__ ktg) {
    __shared__ __align__(16) unsigned short w_l[320*40]; // row stride 40 bf16 (80B)
    __shared__ __align__(16) unsigned short v_l[64*40];
    __shared__ __align__(16) float eg_l[10][36];
    __shared__ float kp_lf[32][33];                      // 32 nodes x 32 m (pad 33)
    int t = threadIdx.x;
    int h = blockIdx.y;
    int n0b = blockIdx.x * 256;
    int lane = t & 63;
    int wb = (t >> 6) * 80;            // wave's km base
    int arow = lane & 15;
    int acol = (lane >> 4) * 8;        // bf16 col offset of the 8-elem fragment
    f32x4 acc[5][4];
    #pragma unroll
    for (int kt = 0; kt < 5; ++kt)
        #pragma unroll
        for (int dt = 0; dt < 4; ++dt)
            acc[kt][dt] = (f32x4){0.f, 0.f, 0.f, 0.f};
    float wsum0 = 0.f, wsum1 = 0.f;
    int k0 = t >> 5, m0 = t & 31;      // row t = k0*32 + m0
    int k1 = 8 + (t >> 5), m1 = t & 31; // row t+256 (t<64)

    for (int st = 0; st < 8; ++st) {
        int n0 = n0b + st * 32;
        __syncthreads();               // prev tile consumed by MFMA
        #pragma unroll
        for (int i = 0; i < 2; ++i) {
            int flat = t + i*256;
            if (flat < 320) {
                int kk = flat % 10, n = flat / 10;
                float e = 0.f;
                if (n0 + n < NN) e = __expf(g[(size_t)(n0+n)*40 + h*10 + kk]);
                eg_l[kk][n] = e;
            }
        }
        {
            int d = t >> 2, seg = t & 3;
            uint4 vv = *(const uint4*)(vT + (size_t)(h*64 + d)*VTS + n0 + seg*8);
            *(uint4*)(&v_l[d*40 + seg*8]) = vv;
        }
        if (t < 128) {
            int n = t >> 2, seg = t & 3;
            int gn = n0 + n;
            if (gn < NN) {
                uint4 kv = *(const uint4*)(kp_bf + (size_t)gn*128 + h*32 + seg*8);
                unsigned uu[4] = {kv.x, kv.y, kv.z, kv.w};
                #pragma unroll
                for (int j = 0; j < 4; ++j) {
                    kp_lf[n][seg*8 + j*2]     = __uint_as_float(uu[j] << 16);
                    kp_lf[n][seg*8 + j*2 + 1] = __uint_as_float(uu[j] & 0xFFFF0000u);
                }
            } else {
                #pragma unroll
                for (int j = 0; j < 8; ++j) kp_lf[n][seg*8 + j] = 0.f;
            }
        }
        __syncthreads();
        {
            // row t
            {
                unsigned dw[16];
                float s = 0.f;
                #pragma unroll
                for (int c = 0; c < 16; ++c) {
                    float kpa = kp_lf[c*2][m0];
                    float kpc = kp_lf[c*2+1][m0];
                    unsigned ua = __float_as_uint(kpa * eg_l[k0][c*2]);
                    unsigned ub = __float_as_uint(kpc * eg_l[k0][c*2+1]);
                    s += __uint_as_float(ua & 0xFFFF0000u) + __uint_as_float(ub & 0xFFFF0000u);
                    dw[c] = (ua >> 16) | (ub & 0xFFFF0000u);
                }
                wsum0 += s;
                uint4* wp = (uint4*)(&w_l[t*40]);
                wp[0] = make_uint4(dw[0], dw[1], dw[2],  dw[3]);
                wp[1] = make_uint4(dw[4], dw[5], dw[6],  dw[7]);
                wp[2] = make_uint4(dw[8], dw[9], dw[10], dw[11]);
                wp[3] = make_uint4(dw[12],dw[13],dw[14], dw[15]);
            }
            if (t < 64) {
                unsigned dw[16];
                float s = 0.f;
                #pragma unroll
                for (int c = 0; c < 16; ++c) {
                    float kpa = kp_lf[c*2][m1];
                    float kpc = kp_lf[c*2+1][m1];
                    unsigned ua = __float_as_uint(kpa * eg_l[k1][c*2]);
                    unsigned ub = __float_as_uint(kpc * eg_l[k1][c*2+1]);
                    s += __uint_as_float(ua & 0xFFFF0000u) + __uint_as_float(ub & 0xFFFF0000u);
                    dw[c] = (ua >> 16) | (ub & 0xFFFF0000u);
                }
                wsum1 += s;
                uint4* wp = (uint4*)(&w_l[(t + 256)*40]);
                wp[0] = make_uint4(dw[0], dw[1], dw[2],  dw[3]);
                wp[1] = make_uint4(dw[4], dw[5], dw[6],  dw[7]);
                wp[2] = make_uint4(dw[8], dw[9], dw[10], dw[11]);
                wp[3] = make_uint4(dw[12],dw[13],dw[14], dw[15]);
            }
        }
        __syncthreads();
        bf16x8 Bf[4];
        #pragma unroll
        for (int dt = 0; dt < 4; ++dt)
            Bf[dt] = *(const bf16x8*)(&v_l[(dt*16 + arow)*40 + acol]);
        #pragma unroll
        for (int kt = 0; kt < 5; ++kt) {
            bf16x8 Af = *(const bf16x8*)(&w_l[(wb + kt*16 + arow)*40 + acol]);
            #pragma unroll
            for (int dt = 0; dt < 4; ++dt)
                acc[kt][dt] = __builtin_amdgcn_mfma_f32_16x16x32_bf16(Af, Bf[dt], acc[kt][dt], 0, 0, 0);
        }
    }
    {
        int orow = (lane >> 4) * 4;
        int ocol = lane & 15;
        float* kb = kvs + h*KM*64;
        #pragma unroll
        for (int kt = 0; kt < 5; ++kt)
            #pragma unroll
            for (int dt = 0; dt < 4; ++dt)
                #pragma unroll
                for (int r = 0; r < 4; ++r)
                    atomicAdd(&kb[(wb + kt*16 + orow + r)*64 + dt*16 + ocol], acc[kt][dt][r]);
        atomicAdd(&ktg[h*KM + t], wsum0);
        if (t < 64) atomicAdd(&ktg[h*KM + 256 + t], wsum1);
    }
}

// ---------- kvs_bfT[h][d][km] = bf16(kvs[h][km][d])  (B operand for k_znext_mfma)
__global__ void k_kvsbf(const float* __restrict__ kvs, unsigned short* __restrict__ kvs_bfT) {
    int idx = blockIdx.x*256 + threadIdx.x;   // 320 blocks -> 81920 exact
    int h = idx / 20480;
    int rem = idx - h*20480;
    int d = rem / 320;
    int km = rem - d*320;
    kvs_bfT[idx] = f2bf(kvs[(size_t)h*20480 + km*64 + d]);
}

// ---------- znext via MFMA: A[n][k*32+m] = qpn[n][m]*rd[n][k] (bf16, LDS),
// B = kvs_bfT[h][d][km]. D[n][d] = znext. Also emits qpn_bf.
__global__ __launch_bounds__(256) void k_znext_mfma(const float* __restrict__ qp,
                        const unsigned short* __restrict__ kvs_bfT,
                        const float* __restrict__ ktg, const float* __restrict__ kp_sum,
                        float* __restrict__ znext, unsigned short* __restrict__ qpn_bf) {
    __shared__ __align__(16) unsigned short A_l[64*328];
    __shared__ float ktg_l[320];
    __shared__ float ksum_l[32];
    int t = threadIdx.x;
    int h = blockIdx.y;
    int n0 = blockIdx.x * 64;
    ktg_l[t] = ktg[h*KM + t];
    if (t < 64) ktg_l[256 + t] = ktg[h*KM + 256 + t];
    if (t < 32) ksum_l[t] = kp_sum[h*32 + t];
    __syncthreads();
    // ---- phase 1: thread = node*4 + p; p owns m in [p*8, p*8+8)
    {
        int node = t >> 2, p = t & 3;
        int n = n0 + node;
        bool ok = (n < NN);
        float q8[8];
        if (ok) {
            const float* qb = qp + (size_t)n*128 + h*32 + p*8;
            float4 a = *(const float4*)(qb);
            float4 b = *(const float4*)(qb + 4);
            q8[0]=a.x; q8[1]=a.y; q8[2]=a.z; q8[3]=a.w;
            q8[4]=b.x; q8[5]=b.y; q8[6]=b.z; q8[7]=b.w;
        } else {
            #pragma unroll
            for (int j = 0; j < 8; ++j) q8[j] = 0.f;
        }
        float part = 0.f;
        #pragma unroll
        for (int j = 0; j < 8; ++j) part = fmaf(q8[j], ksum_l[p*8 + j], part);
        part += __shfl_xor(part, 1); part += __shfl_xor(part, 2);
        float rn = ok ? (1.f / part) : 0.f;
        #pragma unroll
        for (int j = 0; j < 8; ++j) q8[j] *= rn;
        if (ok) {
            unsigned ob[4];
            #pragma unroll
            for (int c = 0; c < 4; ++c)
                ob[c] = (unsigned)f2bf(q8[c*2]) | ((unsigned)f2bf(q8[c*2+1]) << 16);
            *(uint4*)(qpn_bf + (size_t)n*128 + h*32 + p*8) = make_uint4(ob[0], ob[1], ob[2], ob[3]);
        }
        #pragma unroll
        for (int k = 0; k < 10; ++k) {
            float dp = 0.f;
            #pragma unroll
            for (int j = 0; j < 8; ++j) dp = fmaf(q8[j], ktg_l[k*32 + p*8 + j], dp);
            dp += __shfl_xor(dp, 1); dp += __shfl_xor(dp, 2);
            float rd = ok ? (1.f / (dp * 10.f)) : 0.f;
            unsigned ob[4];
            #pragma unroll
            for (int c = 0; c < 4; ++c)
                ob[c] = (unsigned)f2bf(q8[c*2]*rd) | ((unsigned)f2bf(q8[c*2+1]*rd) << 16);
            *(uint4*)(&A_l[node*328 + k*32 + p*8]) = make_uint4(ob[0], ob[1], ob[2], ob[3]);
        }
    }
    __syncthreads();
    // ---- phase 2: wave w = 16-d N-tile; 4 M-tiles; 10 K-steps
    {
        int lane = t & 63, w = t >> 6;
        int arow = lane & 15;
        int ao = (lane >> 4) * 8;
        f32x4 acc[4];
        #pragma unroll
        for (int mt = 0; mt < 4; ++mt) acc[mt] = (f32x4){0.f,0.f,0.f,0.f};
        const unsigned short* Bb = kvs_bfT + (size_t)h*20480 + (w*16 + arow)*320;
        #pragma unroll
        for (int ks = 0; ks < 10; ++ks) {
            bf16x8 Bf = *(const bf16x8*)(Bb + ks*32 + ao);
            #pragma unroll
            for (int mt = 0; mt < 4; ++mt) {
                bf16x8 Af = *(const bf16x8*)(&A_l[(mt*16 + arow)*328 + ks*32 + ao]);
                acc[mt] = __builtin_amdgcn_mfma_f32_16x16x32_bf16(Af, Bf, acc[mt], 0, 0, 0);
            }
        }
        #pragma unroll
        for (int mt = 0; mt < 4; ++mt)
            #pragma unroll
            for (int r = 0; r < 4; ++r) {
                int n = n0 + mt*16 + (lane>>4)*4 + r;
                if (n < NN)
                    znext[(size_t)n*256 + h*64 + w*16 + arow] = acc[mt][r];
            }
    }
}

// ---------- FUSED conv + edge over CSR, 2-edge unrolled.
__global__ __launch_bounds__(256) void k_convedge(const int* __restrict__ offsets,
                        const int2* __restrict__ csr_pack,
                        const int* __restrict__ din, const unsigned short* __restrict__ vr,
                        const unsigned short* __restrict__ kp_bf,
                        const unsigned short* __restrict__ qpn_bf,
                        const float* __restrict__ brb, float* __restrict__ znext,
                        float* __restrict__ A) {
    __shared__ unsigned short qpn_l[4][128];
    int t = threadIdx.x;
    int w = t >> 6, lane = t & 63;
    int col = blockIdx.x*4 + w;          // grid exact: col < NN always
    if (lane < 8) {
        uint4 q4 = *(const uint4*)(qpn_bf + (size_t)col*128 + lane*8);
        *(uint4*)(&qpn_l[w][lane*8]) = q4;
    }
    __syncthreads();
    int s0 = offsets[col], s1 = offsets[col+1];
    int hq = (lane & 31) >> 3;
    float qv0, qv1, qv2, qv3;
    {
        ushort4 qq = *(const ushort4*)(&qpn_l[w][hq*32 + (lane & 7)*4]);
        qv0 = bf2f(qq.x); qv1 = bf2f(qq.y); qv2 = bf2f(qq.z); qv3 = bf2f(qq.w);
    }
    bool dowrite = (lane < 32) && ((lane & 7) == 0);
    float a0 = 0.f, a1 = 0.f, a2 = 0.f, a3 = 0.f;
    int j = s0;
    for (; j + 2 <= s1; j += 2) {
        int2 p0 = csr_pack[j];
        int2 p1 = csr_pack[j+1];
        ushort4 u0 = *(const ushort4*)(vr + (size_t)p0.x*256 + lane*4);
        ushort4 u1 = *(const ushort4*)(vr + (size_t)p1.x*256 + lane*4);
        ushort4 k0 = *(const ushort4*)(kp_bf + (size_t)p0.x*128 + (lane & 31)*4);
        ushort4 k1 = *(const ushort4*)(kp_bf + (size_t)p1.x*128 + (lane & 31)*4);
        a0 += bf2f(u0.x) + bf2f(u1.x);
        a1 += bf2f(u0.y) + bf2f(u1.y);
        a2 += bf2f(u0.z) + bf2f(u1.z);
        a3 += bf2f(u0.w) + bf2f(u1.w);
        float d0 = qv0*bf2f(k0.x) + qv1*bf2f(k0.y) + qv2*bf2f(k0.z) + qv3*bf2f(k0.w);
        float d1 = qv0*bf2f(k1.x) + qv1*bf2f(k1.y) + qv2*bf2f(k1.z) + qv3*bf2f(k1.w);
        d0 += __shfl_xor(d0, 1); d1 += __shfl_xor(d1, 1);
        d0 += __shfl_xor(d0, 2); d1 += __shfl_xor(d1, 2);
        d0 += __shfl_xor(d0, 4); d1 += __shfl_xor(d1, 4);
        if (dowrite) {
            A[(size_t)p0.y*4 + hq] = d0;
            A[(size_t)p1.y*4 + hq] = d1;
        }
    }
    if (j < s1) {
        int2 p0 = csr_pack[j];
        ushort4 u0 = *(const ushort4*)(vr + (size_t)p0.x*256 + lane*4);
        ushort4 k0 = *(const ushort4*)(kp_bf + (size_t)p0.x*128 + (lane & 31)*4);
        a0 += bf2f(u0.x); a1 += bf2f(u0.y); a2 += bf2f(u0.z); a3 += bf2f(u0.w);
        float d0 = qv0*bf2f(k0.x) + qv1*bf2f(k0.y) + qv2*bf2f(k0.z) + qv3*bf2f(k0.w);
        d0 += __shfl_xor(d0, 1); d0 += __shfl_xor(d0, 2); d0 += __shfl_xor(d0, 4);
        if (dowrite) A[(size_t)p0.y*4 + hq] = d0;
    }
    if (s0 == s1) return;
    int h = lane >> 4;
    float sig = 1.f / (1.f + __expf(-brb[h]));
    float sc = sig * rsqrtf((float)din[col]);
    float* zp = znext + (size_t)col*256 + lane*4;
    float4 zv = *(float4*)zp;
    zv.x += sc*a0; zv.y += sc*a1; zv.z += sc*a2; zv.w += sc*a3;
    *(float4*)zp = zv;
}

// ---------- vr[row] = rsd[row] * v[row], bf16-compressed
__global__ __launch_bounds__(256) void k_vr(const float* __restrict__ vbuf,
                      const float* __restrict__ rsd, unsigned short* __restrict__ vr) {
    int t = threadIdx.x;
    int row = blockIdx.x*4 + (t >> 6);
    int lane = t & 63;
    float rs = rsd[row];
    float4 v4 = *(const float4*)(vbuf + (size_t)row*256 + lane*4);
    ushort4 o;
    o.x = f2bf(rs * v4.x);
    o.y = f2bf(rs * v4.y);
    o.z = f2bf(rs * v4.z);
    o.w = f2bf(rs * v4.w);
    *(ushort4*)(vr + (size_t)row*256 + lane*4) = o;
}

// ---------- out[n][o] = sum_f znext[n][f] * Wo[o][f] + Wob[o]
__global__ __launch_bounds__(256) void k_out(const float* __restrict__ znext, const float* __restrict__ WoT,
                      const float* __restrict__ Wob, float* __restrict__ out) {
    int n = blockIdx.x*256 + threadIdx.x;
    if (n >= NN) return;
    float acc[64];
    #pragma unroll
    for (int o = 0; o < 64; ++o) acc[o] = Wob[o];
    const float* zr = znext + (size_t)n*256;
    for (int fc = 0; fc < 64; ++fc) {
        float4 z4 = *(const float4*)(zr + fc*4);
        float zz[4] = {z4.x, z4.y, z4.z, z4.w};
        #pragma unroll
        for (int j = 0; j < 4; ++j) {
            const float* wr = WoT + (fc*4+j)*64;
            #pragma unroll
            for (int o = 0; o < 64; ++o)
                acc[o] = fmaf(zz[j], wr[o], acc[o]);
        }
    }
    float* ob = out + (size_t)n*64;
    #pragma unroll
    for (int o = 0; o < 64; ++o) ob[o] = acc[o];
}

extern "C" void kernel_launch(void* const* d_in, const int* in_sizes, int n_in,
                              void* d_out, int out_size, void* d_ws, size_t ws_size,
                              hipStream_t stream) {
    const float* z    = (const float*)d_in[0];
    const int*   ei   = (const int*)d_in[1];
    const float* Wq   = (const float*)d_in[2];
    const float* Wqb  = (const float*)d_in[3];
    const float* Wk   = (const float*)d_in[4];
    const float* Wkb  = (const float*)d_in[5];
    const float* Wv   = (const float*)d_in[6];
    const float* Wvb  = (const float*)d_in[7];
    const float* Wo   = (const float*)d_in[8];
    const float* Wob  = (const float*)d_in[9];
    const float* brb  = (const float*)d_in[10];
    const float* proj = (const float*)d_in[11];
    const float* g    = (const float*)d_in[12];
    float* out = (float*)d_out;
    float* A   = out + (size_t)NN*64;
    float* ws  = (float*)d_ws;

    float* Wt      = ws;                 // 131072
    float* bext    = ws + 131072;        // 1024
    float* WoT     = ws + 132096;        // 16384
    float* kvs     = ws + 148480;        // 81920
    float* ktg     = ws + 230400;        // 1280
    float* kp_sum  = ws + 231680;        // 128
    unsigned* stab = (unsigned*)(ws + 231808); // 4
    int* din       = (int*)(ws + 231812);      // 50000
    int* dout_     = (int*)(ws + 281812);      // 50000
    float* vbuf    = ws + 331840;        // 12.8M
    float* qp      = ws + 13131840;      // 6.4M
    float* kpb     = ws + 19531840;      // 6.4M (raw dash; dead after k_kp)
    float* znext   = ws + 25931840;      // 12.8M
    int* offsets   = (int*)(ws + 38731840);    // 50001 (pad to 50004)
    int* cursor    = (int*)(ws + 38781844);    // 50000
    int* bsum      = (int*)(ws + 38831844);    // 196
    int* boff      = (int*)(ws + 38832040);    // 196
    float* rsd     = ws + 38832236;            // 50000 -> 38882236
    unsigned short* Wcb = (unsigned short*)(ws + 38882240);      // 262144 ushorts
    unsigned short* kvs_bfT = (unsigned short*)(ws + 39013312);  // 81920 ushorts -> end ~39054272
    // aliases:
    //   vT  (256 x 50176 bf16 = 25.7MB) -> znext region (dead until k_znext_mfma)
    //   csr_pack (800000 int2)          -> kpb region [0 .. 1600000)
    //   A_scratch (3.2M floats)         -> kpb region [1600000 .. 4800000)
    //   vr  (12.8M bf16)                -> qp region (fp32 qp dead after k_znext_mfma)
    //   kp_bf  (6.4M bf16)              -> A segment of d_out
    //   qpn_bf (6.4M bf16)              -> out segment of d_out
    unsigned short* vT     = (unsigned short*)znext;
    int2* csr_pack         = (int2*)kpb;
    float* A_scratch       = kpb + 1600000;
    unsigned short* vr     = (unsigned short*)qp;
    unsigned short* kp_bf  = (unsigned short*)A;
    unsigned short* qpn_bf = (unsigned short*)out;

    hipMemsetAsync(ws + 148480, 0, (size_t)(331840 - 148480)*sizeof(float), stream);
    k_prep<<<128, 256, 0, stream>>>(Wq, Wqb, Wk, Wkb, Wv, Wvb, Wo, proj, Wt, bext, WoT);
    k_prep2<<<512, 256, 0, stream>>>(Wt, Wcb);
    k_ztail<<<88, 256, 0, stream>>>((unsigned*)vT);
    k_qkv_mfma<<<391, 256, 0, stream>>>(z, Wcb, bext, vbuf, qp, kpb, stab);
    k_deg<<<3125, 256, 0, stream>>>(ei, din, dout_);
    k_scan_part<<<196, 256, 0, stream>>>(din, bsum);
    k_scan_top<<<1, 64, 0, stream>>>(bsum, boff);
    k_scan_fin<<<196, 256, 0, stream>>>(din, boff, offsets, cursor, dout_, rsd);
    k_kp<<<512, 256, 0, stream>>>(kpb, stab, kp_sum, kp_bf);      // raw kpb dead after this
    k_scatter<<<3125, 256, 0, stream>>>(ei, cursor, csr_pack);
    k_vt<<<dim3(782, 4), 256, 0, stream>>>(vbuf, vT);
    k_kvs<<<dim3(KVSNB, 4), 256, 0, stream>>>(kp_bf, g, vT, kvs, ktg);
    k_kvsbf<<<320, 256, 0, stream>>>(kvs, kvs_bfT);
    k_znext_mfma<<<dim3(782, 4), 256, 0, stream>>>(qp, kvs_bfT, ktg, kp_sum, znext, qpn_bf);
    k_vr<<<12500, 256, 0, stream>>>(vbuf, rsd, vr);                 // vr aliases qp (dead now)
    k_convedge<<<12500, 256, 0, stream>>>(offsets, csr_pack, din, vr, kp_bf,
                                          qpn_bf, brb, znext, A_scratch);
    k_out<<<196, 256, 0, stream>>>(znext, WoT, Wob, out);
    hipMemcpyAsync(A, A_scratch, (size_t)EE*4*sizeof(float), hipMemcpyDeviceToDevice, stream);
}

// Round 22
// 659.692 us; speedup vs baseline: 1.0186x; 1.0186x over previous
//
#include <hip/hip_runtime.h>

#define NN 50000
#define EE 800000
#define IND 128
#define NCOL 1024
#define KM 320            // K * Mpad = 10*32
#define M30 30
#define RATIO 0.1825741858f   // 30^-0.5
#define EPSF 1e-6f
#define QKSCALE 0.7071067812f // (1/sqrt(0.25)) * 64^-0.25
#define VTS 50176             // vT row stride (196*256)
#define KVSNB 196             // k_kvs node-chunk blocks (256 nodes each)
#define AST 136               // a-tile LDS row stride in bf16 (2-way-free banks)

typedef __attribute__((ext_vector_type(8))) short bf16x8;
typedef __attribute__((ext_vector_type(4))) float f32x4;

__device__ __forceinline__ unsigned f2s(float f) {
    unsigned u = __float_as_uint(f);
    return (u & 0x80000000u) ? ~u : (u | 0x80000000u);
}
__device__ __forceinline__ float s2f(unsigned s) {
    return __uint_as_float((s & 0x80000000u) ? (s & 0x7fffffffu) : ~s);
}
__device__ __forceinline__ unsigned short f2bf(float f) {   // RTNE fp32->bf16
    unsigned u = __float_as_uint(f);
    unsigned r = u + 0x7fffu + ((u >> 16) & 1u);
    return (unsigned short)(r >> 16);
}
__device__ __forceinline__ float bf2f(unsigned short h) {
    return __uint_as_float(((unsigned)h) << 16);
}

// ---------- prep: Wt[IND][NCOL] (cols: 0-255 s*Wq^T, 256-511 s*Wk^T, 512-767 Wv^T,
// 768-895 Pq[h,m], 896-1023 Pk[h,m]), bias_ext[NCOL], WoT[256][64]
__global__ void k_prep(const float* __restrict__ Wq, const float* __restrict__ Wqb,
                       const float* __restrict__ Wk, const float* __restrict__ Wkb,
                       const float* __restrict__ Wv, const float* __restrict__ Wvb,
                       const float* __restrict__ Wo, const float* __restrict__ proj,
                       float* __restrict__ Wt, float* __restrict__ bext, float* __restrict__ WoT) {
    int i = blockIdx.x;   // 0..127
    int t = threadIdx.x;  // 0..255
    Wt[i*NCOL + t]       = QKSCALE * Wq[t*IND + i];
    Wt[i*NCOL + 256 + t] = QKSCALE * Wk[t*IND + i];
    Wt[i*NCOL + 512 + t] = Wv[t*IND + i];
    {
        const float* W = (t < 128) ? Wq : Wk;
        int c = (t < 128) ? t : (t - 128);
        int h = c >> 5, m = c & 31;
        float val = 0.f;
        if (m < M30) {
            for (int d = 0; d < 64; ++d)
                val += QKSCALE * W[(h*64+d)*IND + i] * proj[m*64 + d];
        }
        Wt[i*NCOL + 768 + t] = val;
    }
    if (t < 128) {
        int f = i*2 + (t >> 6);
        int o = t & 63;
        WoT[f*64 + o] = Wo[o*256 + f];
    }
    if (i == 0) {
        bext[t]       = QKSCALE * Wqb[t];
        bext[256 + t] = QKSCALE * Wkb[t];
        bext[512 + t] = Wvb[t];
        const float* Bb = (t < 128) ? Wqb : Wkb;
        int c = (t < 128) ? t : (t - 128);
        int h = c >> 5, m = c & 31;
        float val = 0.f;
        if (m < M30) {
            for (int d = 0; d < 64; ++d)
                val += QKSCALE * Bb[h*64+d] * proj[m*64 + d];
        }
        bext[768 + t] = val;
    }
}

// ---------- Wcb: bf16 hi/lo split of Wt, layout [col][k] (MFMA B operand)
__global__ void k_prep2(const float* __restrict__ Wt, unsigned short* __restrict__ Wcb) {
    int idx = blockIdx.x*256 + threadIdx.x;   // 512 blocks -> 131072
    int col = idx >> 7, k = idx & 127;
    float f = Wt[k*NCOL + col];
    unsigned short hi = f2bf(f);
    unsigned short lo = f2bf(f - bf2f(hi));
    Wcb[col*128 + k] = hi;
    Wcb[131072 + col*128 + k] = lo;
}

// ---------- zero vT tail cols [50000,50176) (vT aliases znext; replay determinism)
__global__ void k_ztail(unsigned* __restrict__ vT32) {
    int idx = blockIdx.x*256 + threadIdx.x;  // 88 blocks * 256 = 22528 = 256*88
    int row = idx / 88, c = idx - row*88;
    vT32[(size_t)row * (VTS/2) + (50000/2) + c] = 0u;
}

// ---------- fused QKV+dash GEMM via bf16x2 MFMA (A single-rounded, B hi+lo).
// ROUND-22 (= round-19 verified best, 655us total): 128 nodes/block, plain
// launch_bounds(256). The acc[8][4]=128 accumulator spills (VGPR caps at the
// 256 ISA-addressable limit; launch_bounds(256,1) proved this is architectural,
// not occupancy -- round 21), but 16 MFMAs per dependent B-load pair covers L2
// latency and the spill tax (~30us HBM) < latency-exposure tax (64-node: +14us).
__global__ __launch_bounds__(256) void k_qkv_mfma(const float* __restrict__ z,
                      const unsigned short* __restrict__ Wcb, const float* __restrict__ bext,
                      float* __restrict__ vbuf, float* __restrict__ qp, float* __restrict__ kpb,
                      unsigned* __restrict__ stab) {
    __shared__ __align__(16) unsigned short a_hi[128*AST];
    __shared__ float diag_l[2][4][128];   // [q/k][head][node]
    int t = threadIdx.x;
    int n0 = blockIdx.x * 128;
    int w = t >> 6, lane = t & 63;
    #pragma unroll
    for (int half = 0; half < 2; ++half) {
        int node = (t >> 2) + half*64;
        int ks = (t & 3) * 32;
        bool ok = (n0 + node) < NN;
        const float* zr = z + (size_t)(n0 + node)*IND + ks;
        unsigned hbuf[16];
        #pragma unroll
        for (int c = 0; c < 8; ++c) {
            float4 v = ok ? *(const float4*)(zr + c*4) : make_float4(0.f,0.f,0.f,0.f);
            hbuf[c*2]   = (unsigned)f2bf(v.x) | ((unsigned)f2bf(v.y) << 16);
            hbuf[c*2+1] = (unsigned)f2bf(v.z) | ((unsigned)f2bf(v.w) << 16);
        }
        uint4* hp = (uint4*)(&a_hi[node*AST + ks]);
        #pragma unroll
        for (int c = 0; c < 4; ++c)
            hp[c] = make_uint4(hbuf[c*4], hbuf[c*4+1], hbuf[c*4+2], hbuf[c*4+3]);
    }
    __syncthreads();
    int arow = lane & 15;
    int ao = (lane >> 4) * 8;
    for (int c = 0; c < 4; ++c) {
        int colbase = c*256 + w*64;
        f32x4 acc[8][4];
        #pragma unroll
        for (int mt = 0; mt < 8; ++mt)
            #pragma unroll
            for (int nt = 0; nt < 4; ++nt)
                acc[mt][nt] = (f32x4){0.f,0.f,0.f,0.f};
        #pragma unroll
        for (int ks = 0; ks < 4; ++ks) {
            int ko = ks*32 + ao;
            bf16x8 Ah[8];
            #pragma unroll
            for (int mt = 0; mt < 8; ++mt)
                Ah[mt] = *(const bf16x8*)(&a_hi[(mt*16 + arow)*AST + ko]);
            #pragma unroll
            for (int nt = 0; nt < 4; ++nt) {
                const unsigned short* bp = Wcb + (size_t)(colbase + nt*16 + arow)*128 + ko;
                bf16x8 Bh = *(const bf16x8*)bp;
                bf16x8 Bl = *(const bf16x8*)(bp + 131072);
                #pragma unroll
                for (int mt = 0; mt < 8; ++mt) {
                    acc[mt][nt] = __builtin_amdgcn_mfma_f32_16x16x32_bf16(Ah[mt], Bh, acc[mt][nt], 0, 0, 0);
                    acc[mt][nt] = __builtin_amdgcn_mfma_f32_16x16x32_bf16(Ah[mt], Bl, acc[mt][nt], 0, 0, 0);
                }
            }
        }
        float bv[4];
        #pragma unroll
        for (int nt = 0; nt < 4; ++nt) bv[nt] = bext[colbase + nt*16 + arow];
        #pragma unroll
        for (int mt = 0; mt < 8; ++mt)
            #pragma unroll
            for (int nt = 0; nt < 4; ++nt)
                #pragma unroll
                for (int r = 0; r < 4; ++r)
                    acc[mt][nt][r] += bv[nt];
        if (c < 2) {
            #pragma unroll
            for (int mt = 0; mt < 8; ++mt) {
                #pragma unroll
                for (int r = 0; r < 4; ++r) {
                    float s = 0.f;
                    #pragma unroll
                    for (int nt = 0; nt < 4; ++nt) s += acc[mt][nt][r]*acc[mt][nt][r];
                    s += __shfl_xor(s, 1); s += __shfl_xor(s, 2);
                    s += __shfl_xor(s, 4); s += __shfl_xor(s, 8);
                    if (arow == 0) diag_l[c][w][mt*16 + (lane>>4)*4 + r] = 0.5f*s;
                }
            }
        } else if (c == 2) {
            #pragma unroll
            for (int mt = 0; mt < 8; ++mt)
                #pragma unroll
                for (int r = 0; r < 4; ++r) {
                    int node = n0 + mt*16 + (lane>>4)*4 + r;
                    if (node < NN) {
                        #pragma unroll
                        for (int nt = 0; nt < 4; ++nt)
                            vbuf[(size_t)node*256 + w*64 + nt*16 + arow] = acc[mt][nt][r];
                    }
                }
        } else {
            int hh = (w & 1) * 2;
            if (w < 2) {
                #pragma unroll
                for (int p = 0; p < 2; ++p) {
                    int h = hh + p;
                    #pragma unroll
                    for (int mt = 0; mt < 8; ++mt) {
                        #pragma unroll
                        for (int r = 0; r < 4; ++r) {
                            int row = mt*16 + (lane>>4)*4 + r;
                            float dg = diag_l[0][h][row];
                            float mx = fmaxf(acc[mt][2*p][r],
                                             (arow < 14) ? acc[mt][2*p+1][r] : -3.0e38f);
                            mx = fmaxf(mx, __shfl_xor(mx, 1)); mx = fmaxf(mx, __shfl_xor(mx, 2));
                            mx = fmaxf(mx, __shfl_xor(mx, 4)); mx = fmaxf(mx, __shfl_xor(mx, 8));
                            int node = n0 + row;
                            if (node < NN) {
                                #pragma unroll
                                for (int q2 = 0; q2 < 2; ++q2) {
                                    int m = q2*16 + arow;
                                    float val = 0.f;
                                    if (m < M30)
                                        val = RATIO * (__expf(acc[mt][2*p+q2][r] - dg - mx) + EPSF);
                                    qp[(size_t)node*128 + h*32 + m] = val;
                                }
                            }
                        }
                    }
                }
            } else {
                #pragma unroll
                for (int p = 0; p < 2; ++p) {
                    int h = hh + p;
                    float smax = -3.0e38f;
                    #pragma unroll
                    for (int mt = 0; mt < 8; ++mt) {
                        #pragma unroll
                        for (int r = 0; r < 4; ++r) {
                            int row = mt*16 + (lane>>4)*4 + r;
                            float dg = diag_l[1][h][row];
                            int node = n0 + row;
                            if (node < NN) {
                                #pragma unroll
                                for (int q2 = 0; q2 < 2; ++q2) {
                                    int m = q2*16 + arow;
                                    float d = acc[mt][2*p+q2][r];
                                    bool valid = (m < M30);
                                    kpb[(size_t)node*128 + h*32 + m] = valid ? (d - dg) : 0.f;
                                    if (valid) smax = fmaxf(smax, d);
                                }
                            }
                        }
                    }
                    smax = fmaxf(smax, __shfl_xor(smax, 1));  smax = fmaxf(smax, __shfl_xor(smax, 2));
                    smax = fmaxf(smax, __shfl_xor(smax, 4));  smax = fmaxf(smax, __shfl_xor(smax, 8));
                    smax = fmaxf(smax, __shfl_xor(smax, 16)); smax = fmaxf(smax, __shfl_xor(smax, 32));
                    if (lane == 0) atomicMax(&stab[h], f2s(smax));
                }
            }
        }
        __syncthreads();
    }
}

// ---------- vT[c][n] = bf16(vbuf[n][c]) tiled transpose (64x64 tiles via LDS)
__global__ __launch_bounds__(256) void k_vt(const float* __restrict__ vbuf,
                      unsigned short* __restrict__ vT) {
    __shared__ unsigned short tile[64][72];
    int t = threadIdx.x;
    int n0 = blockIdx.x * 64;
    int c0 = blockIdx.y * 64;
    {
        int node = t >> 2, cs = (t & 3) * 16;
        bool ok = (n0 + node) < NN;
        const float* vr = vbuf + (size_t)(n0 + node)*256 + c0 + cs;
        #pragma unroll
        for (int cc = 0; cc < 4; ++cc) {
            float4 v = ok ? *(const float4*)(vr + cc*4) : make_float4(0.f,0.f,0.f,0.f);
            unsigned u0 = (unsigned)f2bf(v.x) | ((unsigned)f2bf(v.y) << 16);
            unsigned u1 = (unsigned)f2bf(v.z) | ((unsigned)f2bf(v.w) << 16);
            *(unsigned*)(&tile[node][cs + cc*4])     = u0;
            *(unsigned*)(&tile[node][cs + cc*4 + 2]) = u1;
        }
    }
    __syncthreads();
    {
        int d = t >> 2, ns = (t & 3) * 16;
        unsigned ob[8];
        #pragma unroll
        for (int i = 0; i < 8; ++i) {
            unsigned short a = tile[ns + i*2][d];
            unsigned short b = tile[ns + i*2 + 1][d];
            ob[i] = (unsigned)a | ((unsigned)b << 16);
        }
        unsigned short* op = vT + (size_t)(c0 + d)*VTS + n0 + ns;
        *(uint4*)(op)     = make_uint4(ob[0], ob[1], ob[2], ob[3]);
        *(uint4*)(op + 8) = make_uint4(ob[4], ob[5], ob[6], ob[7]);
    }
}

__global__ void k_deg(const int* __restrict__ ei, int* __restrict__ din, int* __restrict__ dout) {
    int e = blockIdx.x*256 + threadIdx.x;
    if (e < EE) {
        atomicAdd(&dout[ei[e]], 1);
        atomicAdd(&din[ei[EE + e]], 1);
    }
}

// ---------- prefix sum over din (3-kernel scan) ----------
__global__ void k_scan_part(const int* __restrict__ din, int* __restrict__ bsum) {
    __shared__ int red[256];
    int t = threadIdx.x;
    int i = blockIdx.x*256 + t;
    red[t] = (i < NN) ? din[i] : 0;
    __syncthreads();
    for (int off = 128; off >= 1; off >>= 1) {
        if (t < off) red[t] += red[t+off];
        __syncthreads();
    }
    if (t == 0) bsum[blockIdx.x] = red[0];
}
__global__ void k_scan_top(const int* __restrict__ bsum, int* __restrict__ boff) {
    if (threadIdx.x == 0) {
        int acc = 0;
        for (int b = 0; b < 196; ++b) { boff[b] = acc; acc += bsum[b]; }
    }
}
// scan finish + rsd = rsqrt(dout) (k_rs folded in)
__global__ void k_scan_fin(const int* __restrict__ din, const int* __restrict__ boff,
                           int* __restrict__ offsets, int* __restrict__ cursor,
                           const int* __restrict__ dout_, float* __restrict__ rsd) {
    __shared__ int s[256];
    int t = threadIdx.x;
    int i = blockIdx.x*256 + t;
    if (i < NN) {
        int d = dout_[i];
        rsd[i] = d > 0 ? rsqrtf((float)d) : 0.f;
    }
    int v = (i < NN) ? din[i] : 0;
    s[t] = v;
    __syncthreads();
    for (int off = 1; off < 256; off <<= 1) {
        int add = (t >= off) ? s[t-off] : 0;
        __syncthreads();
        s[t] += add;
        __syncthreads();
    }
    int excl = s[t] - v + boff[blockIdx.x];
    if (i < NN) { offsets[i] = excl; cursor[i] = excl; }
    if (i == NN-1) offsets[NN] = excl + v;
}

// scatter (row, eid) packed as int2 into CSR-by-col order
__global__ void k_scatter(const int* __restrict__ ei, int* __restrict__ cursor,
                          int2* __restrict__ csr_pack) {
    int e = blockIdx.x*256 + threadIdx.x;
    if (e < EE) {
        int col = ei[EE + e];
        int pos = atomicAdd(&cursor[col], 1);
        csr_pack[pos] = make_int2(ei[e], e);
    }
}

// ---------- finish kp = ratio*(exp(dash-diag-stab)+eps) -> kp_bf (bf16); kp_sum[h][m]
__global__ void k_kp(const float* __restrict__ kpb, const unsigned* __restrict__ stab,
                     float* __restrict__ kp_sum, unsigned short* __restrict__ kp_bf) {
    __shared__ float red[256];
    int t = threadIdx.x;
    int hm = t & 127;
    int h = hm >> 5, m = hm & 31;
    float st = s2f(stab[h]);
    float ksum = 0.f;
    const int total = NN*128;
    for (int idx = blockIdx.x*256 + t; idx < total; idx += gridDim.x*256) {
        float val = kpb[idx];
        float kpv = 0.f;
        if (m < M30) kpv = RATIO * (__expf(val - st) + EPSF);
        kp_bf[idx] = f2bf(kpv);
        ksum += kpv;
    }
    red[t] = ksum;
    __syncthreads();
    if (t < 128) atomicAdd(&kp_sum[hm], red[t] + red[t+128]);
}

// ---------- kvs[h][km][d] = sum_n w[n,km]*v[n,d] via MFMA (16x16x32 bf16).
__global__ __launch_bounds__(256) void k_kvs(const unsigned short* __restrict__ kp_bf,
                      const float* __restrict__ g, const unsigned short* __restrict__ vT,
                      float* __restrict__ kvs, float* __restrict__ ktg) {
    __shared__ __align__(16) unsigned short w_l[320*40]; // row stride 40 bf16 (80B)
    __shared__ __align__(16) unsigned short v_l[64*40];
    __shared__ __align__(16) float eg_l[10][36];
    __shared__ float kp_lf[32][33];                      // 32 nodes x 32 m (pad 33)
    int t = threadIdx.x;
    int h = blockIdx.y;
    int n0b = blockIdx.x * 256;
    int lane = t & 63;
    int wb = (t >> 6) * 80;            // wave's km base
    int arow = lane & 15;
    int acol = (lane >> 4) * 8;        // bf16 col offset of the 8-elem fragment
    f32x4 acc[5][4];
    #pragma unroll
    for (int kt = 0; kt < 5; ++kt)
        #pragma unroll
        for (int dt = 0; dt < 4; ++dt)
            acc[kt][dt] = (f32x4){0.f, 0.f, 0.f, 0.f};
    float wsum0 = 0.f, wsum1 = 0.f;
    int k0 = t >> 5, m0 = t & 31;      // row t = k0*32 + m0
    int k1 = 8 + (t >> 5), m1 = t & 31; // row t+256 (t<64)

    for (int st = 0; st < 8; ++st) {
        int n0 = n0b + st * 32;
        __syncthreads();               // prev tile consumed by MFMA
        #pragma unroll
        for (int i = 0; i < 2; ++i) {
            int flat = t + i*256;
            if (flat < 320) {
                int kk = flat % 10, n = flat / 10;
                float e = 0.f;
                if (n0 + n < NN) e = __expf(g[(size_t)(n0+n)*40 + h*10 + kk]);
                eg_l[kk][n] = e;
            }
        }
        {
            int d = t >> 2, seg = t & 3;
            uint4 vv = *(const uint4*)(vT + (size_t)(h*64 + d)*VTS + n0 + seg*8);
            *(uint4*)(&v_l[d*40 + seg*8]) = vv;
        }
        if (t < 128) {
            int n = t >> 2, seg = t & 3;
            int gn = n0 + n;
            if (gn < NN) {
                uint4 kv = *(const uint4*)(kp_bf + (size_t)gn*128 + h*32 + seg*8);
                unsigned uu[4] = {kv.x, kv.y, kv.z, kv.w};
                #pragma unroll
                for (int j = 0; j < 4; ++j) {
                    kp_lf[n][seg*8 + j*2]     = __uint_as_float(uu[j] << 16);
                    kp_lf[n][seg*8 + j*2 + 1] = __uint_as_float(uu[j] & 0xFFFF0000u);
                }
            } else {
                #pragma unroll
                for (int j = 0; j < 8; ++j) kp_lf[n][seg*8 + j] = 0.f;
            }
        }
        __syncthreads();
        {
            // row t
            {
                unsigned dw[16];
                float s = 0.f;
                #pragma unroll
                for (int c = 0; c < 16; ++c) {
                    float kpa = kp_lf[c*2][m0];
                    float kpc = kp_lf[c*2+1][m0];
                    unsigned ua = __float_as_uint(kpa * eg_l[k0][c*2]);
                    unsigned ub = __float_as_uint(kpc * eg_l[k0][c*2+1]);
                    s += __uint_as_float(ua & 0xFFFF0000u) + __uint_as_float(ub & 0xFFFF0000u);
                    dw[c] = (ua >> 16) | (ub & 0xFFFF0000u);
                }
                wsum0 += s;
                uint4* wp = (uint4*)(&w_l[t*40]);
                wp[0] = make_uint4(dw[0], dw[1], dw[2],  dw[3]);
                wp[1] = make_uint4(dw[4], dw[5], dw[6],  dw[7]);
                wp[2] = make_uint4(dw[8], dw[9], dw[10], dw[11]);
                wp[3] = make_uint4(dw[12],dw[13],dw[14], dw[15]);
            }
            if (t < 64) {
                unsigned dw[16];
                float s = 0.f;
                #pragma unroll
                for (int c = 0; c < 16; ++c) {
                    float kpa = kp_lf[c*2][m1];
                    float kpc = kp_lf[c*2+1][m1];
                    unsigned ua = __float_as_uint(kpa * eg_l[k1][c*2]);
                    unsigned ub = __float_as_uint(kpc * eg_l[k1][c*2+1]);
                    s += __uint_as_float(ua & 0xFFFF0000u) + __uint_as_float(ub & 0xFFFF0000u);
                    dw[c] = (ua >> 16) | (ub & 0xFFFF0000u);
                }
                wsum1 += s;
                uint4* wp = (uint4*)(&w_l[(t + 256)*40]);
                wp[0] = make_uint4(dw[0], dw[1], dw[2],  dw[3]);
                wp[1] = make_uint4(dw[4], dw[5], dw[6],  dw[7]);
                wp[2] = make_uint4(dw[8], dw[9], dw[10], dw[11]);
                wp[3] = make_uint4(dw[12],dw[13],dw[14], dw[15]);
            }
        }
        __syncthreads();
        bf16x8 Bf[4];
        #pragma unroll
        for (int dt = 0; dt < 4; ++dt)
            Bf[dt] = *(const bf16x8*)(&v_l[(dt*16 + arow)*40 + acol]);
        #pragma unroll
        for (int kt = 0; kt < 5; ++kt) {
            bf16x8 Af = *(const bf16x8*)(&w_l[(wb + kt*16 + arow)*40 + acol]);
            #pragma unroll
            for (int dt = 0; dt < 4; ++dt)
                acc[kt][dt] = __builtin_amdgcn_mfma_f32_16x16x32_bf16(Af, Bf[dt], acc[kt][dt], 0, 0, 0);
        }
    }
    {
        int orow = (lane >> 4) * 4;
        int ocol = lane & 15;
        float* kb = kvs + h*KM*64;
        #pragma unroll
        for (int kt = 0; kt < 5; ++kt)
            #pragma unroll
            for (int dt = 0; dt < 4; ++dt)
                #pragma unroll
                for (int r = 0; r < 4; ++r)
                    atomicAdd(&kb[(wb + kt*16 + orow + r)*64 + dt*16 + ocol], acc[kt][dt][r]);
        atomicAdd(&ktg[h*KM + t], wsum0);
        if (t < 64) atomicAdd(&ktg[h*KM + 256 + t], wsum1);
    }
}

// ---------- kvs_bfT[h][d][km] = bf16(kvs[h][km][d])  (B operand for k_znext_mfma)
__global__ void k_kvsbf(const float* __restrict__ kvs, unsigned short* __restrict__ kvs_bfT) {
    int idx = blockIdx.x*256 + threadIdx.x;   // 320 blocks -> 81920 exact
    int h = idx / 20480;
    int rem = idx - h*20480;
    int d = rem / 320;
    int km = rem - d*320;
    kvs_bfT[idx] = f2bf(kvs[(size_t)h*20480 + km*64 + d]);
}

// ---------- znext via MFMA: A[n][k*32+m] = qpn[n][m]*rd[n][k] (bf16, LDS),
// B = kvs_bfT[h][d][km]. D[n][d] = znext. Also emits qpn_bf.
__global__ __launch_bounds__(256) void k_znext_mfma(const float* __restrict__ qp,
                        const unsigned short* __restrict__ kvs_bfT,
                        const float* __restrict__ ktg, const float* __restrict__ kp_sum,
                        float* __restrict__ znext, unsigned short* __restrict__ qpn_bf) {
    __shared__ __align__(16) unsigned short A_l[64*328];
    __shared__ float ktg_l[320];
    __shared__ float ksum_l[32];
    int t = threadIdx.x;
    int h = blockIdx.y;
    int n0 = blockIdx.x * 64;
    ktg_l[t] = ktg[h*KM + t];
    if (t < 64) ktg_l[256 + t] = ktg[h*KM + 256 + t];
    if (t < 32) ksum_l[t] = kp_sum[h*32 + t];
    __syncthreads();
    // ---- phase 1: thread = node*4 + p; p owns m in [p*8, p*8+8)
    {
        int node = t >> 2, p = t & 3;
        int n = n0 + node;
        bool ok = (n < NN);
        float q8[8];
        if (ok) {
            const float* qb = qp + (size_t)n*128 + h*32 + p*8;
            float4 a = *(const float4*)(qb);
            float4 b = *(const float4*)(qb + 4);
            q8[0]=a.x; q8[1]=a.y; q8[2]=a.z; q8[3]=a.w;
            q8[4]=b.x; q8[5]=b.y; q8[6]=b.z; q8[7]=b.w;
        } else {
            #pragma unroll
            for (int j = 0; j < 8; ++j) q8[j] = 0.f;
        }
        float part = 0.f;
        #pragma unroll
        for (int j = 0; j < 8; ++j) part = fmaf(q8[j], ksum_l[p*8 + j], part);
        part += __shfl_xor(part, 1); part += __shfl_xor(part, 2);
        float rn = ok ? (1.f / part) : 0.f;
        #pragma unroll
        for (int j = 0; j < 8; ++j) q8[j] *= rn;
        if (ok) {
            unsigned ob[4];
            #pragma unroll
            for (int c = 0; c < 4; ++c)
                ob[c] = (unsigned)f2bf(q8[c*2]) | ((unsigned)f2bf(q8[c*2+1]) << 16);
            *(uint4*)(qpn_bf + (size_t)n*128 + h*32 + p*8) = make_uint4(ob[0], ob[1], ob[2], ob[3]);
        }
        #pragma unroll
        for (int k = 0; k < 10; ++k) {
            float dp = 0.f;
            #pragma unroll
            for (int j = 0; j < 8; ++j) dp = fmaf(q8[j], ktg_l[k*32 + p*8 + j], dp);
            dp += __shfl_xor(dp, 1); dp += __shfl_xor(dp, 2);
            float rd = ok ? (1.f / (dp * 10.f)) : 0.f;
            unsigned ob[4];
            #pragma unroll
            for (int c = 0; c < 4; ++c)
                ob[c] = (unsigned)f2bf(q8[c*2]*rd) | ((unsigned)f2bf(q8[c*2+1]*rd) << 16);
            *(uint4*)(&A_l[node*328 + k*32 + p*8]) = make_uint4(ob[0], ob[1], ob[2], ob[3]);
        }
    }
    __syncthreads();
    // ---- phase 2: wave w = 16-d N-tile; 4 M-tiles; 10 K-steps
    {
        int lane = t & 63, w = t >> 6;
        int arow = lane & 15;
        int ao = (lane >> 4) * 8;
        f32x4 acc[4];
        #pragma unroll
        for (int mt = 0; mt < 4; ++mt) acc[mt] = (f32x4){0.f,0.f,0.f,0.f};
        const unsigned short* Bb = kvs_bfT + (size_t)h*20480 + (w*16 + arow)*320;
        #pragma unroll
        for (int ks = 0; ks < 10; ++ks) {
            bf16x8 Bf = *(const bf16x8*)(Bb + ks*32 + ao);
            #pragma unroll
            for (int mt = 0; mt < 4; ++mt) {
                bf16x8 Af = *(const bf16x8*)(&A_l[(mt*16 + arow)*328 + ks*32 + ao]);
                acc[mt] = __builtin_amdgcn_mfma_f32_16x16x32_bf16(Af, Bf, acc[mt], 0, 0, 0);
            }
        }
        #pragma unroll
        for (int mt = 0; mt < 4; ++mt)
            #pragma unroll
            for (int r = 0; r < 4; ++r) {
                int n = n0 + mt*16 + (lane>>4)*4 + r;
                if (n < NN)
                    znext[(size_t)n*256 + h*64 + w*16 + arow] = acc[mt][r];
            }
    }
}

// ---------- FUSED conv + edge over CSR, 2-edge unrolled.
__global__ __launch_bounds__(256) void k_convedge(const int* __restrict__ offsets,
                        const int2* __restrict__ csr_pack,
                        const int* __restrict__ din, const unsigned short* __restrict__ vr,
                        const unsigned short* __restrict__ kp_bf,
                        const unsigned short* __restrict__ qpn_bf,
                        const float* __restrict__ brb, float* __restrict__ znext,
                        float* __restrict__ A) {
    __shared__ unsigned short qpn_l[4][128];
    int t = threadIdx.x;
    int w = t >> 6, lane = t & 63;
    int col = blockIdx.x*4 + w;          // grid exact: col < NN always
    if (lane < 8) {
        uint4 q4 = *(const uint4*)(qpn_bf + (size_t)col*128 + lane*8);
        *(uint4*)(&qpn_l[w][lane*8]) = q4;
    }
    __syncthreads();
    int s0 = offsets[col], s1 = offsets[col+1];
    int hq = (lane & 31) >> 3;
    float qv0, qv1, qv2, qv3;
    {
        ushort4 qq = *(const ushort4*)(&qpn_l[w][hq*32 + (lane & 7)*4]);
        qv0 = bf2f(qq.x); qv1 = bf2f(qq.y); qv2 = bf2f(qq.z); qv3 = bf2f(qq.w);
    }
    bool dowrite = (lane < 32) && ((lane & 7) == 0);
    float a0 = 0.f, a1 = 0.f, a2 = 0.f, a3 = 0.f;
    int j = s0;
    for (; j + 2 <= s1; j += 2) {
        int2 p0 = csr_pack[j];
        int2 p1 = csr_pack[j+1];
        ushort4 u0 = *(const ushort4*)(vr + (size_t)p0.x*256 + lane*4);
        ushort4 u1 = *(const ushort4*)(vr + (size_t)p1.x*256 + lane*4);
        ushort4 k0 = *(const ushort4*)(kp_bf + (size_t)p0.x*128 + (lane & 31)*4);
        ushort4 k1 = *(const ushort4*)(kp_bf + (size_t)p1.x*128 + (lane & 31)*4);
        a0 += bf2f(u0.x) + bf2f(u1.x);
        a1 += bf2f(u0.y) + bf2f(u1.y);
        a2 += bf2f(u0.z) + bf2f(u1.z);
        a3 += bf2f(u0.w) + bf2f(u1.w);
        float d0 = qv0*bf2f(k0.x) + qv1*bf2f(k0.y) + qv2*bf2f(k0.z) + qv3*bf2f(k0.w);
        float d1 = qv0*bf2f(k1.x) + qv1*bf2f(k1.y) + qv2*bf2f(k1.z) + qv3*bf2f(k1.w);
        d0 += __shfl_xor(d0, 1); d1 += __shfl_xor(d1, 1);
        d0 += __shfl_xor(d0, 2); d1 += __shfl_xor(d1, 2);
        d0 += __shfl_xor(d0, 4); d1 += __shfl_xor(d1, 4);
        if (dowrite) {
            A[(size_t)p0.y*4 + hq] = d0;
            A[(size_t)p1.y*4 + hq] = d1;
        }
    }
    if (j < s1) {
        int2 p0 = csr_pack[j];
        ushort4 u0 = *(const ushort4*)(vr + (size_t)p0.x*256 + lane*4);
        ushort4 k0 = *(const ushort4*)(kp_bf + (size_t)p0.x*128 + (lane & 31)*4);
        a0 += bf2f(u0.x); a1 += bf2f(u0.y); a2 += bf2f(u0.z); a3 += bf2f(u0.w);
        float d0 = qv0*bf2f(k0.x) + qv1*bf2f(k0.y) + qv2*bf2f(k0.z) + qv3*bf2f(k0.w);
        d0 += __shfl_xor(d0, 1); d0 += __shfl_xor(d0, 2); d0 += __shfl_xor(d0, 4);
        if (dowrite) A[(size_t)p0.y*4 + hq] = d0;
    }
    if (s0 == s1) return;
    int h = lane >> 4;
    float sig = 1.f / (1.f + __expf(-brb[h]));
    float sc = sig * rsqrtf((float)din[col]);
    float* zp = znext + (size_t)col*256 + lane*4;
    float4 zv = *(float4*)zp;
    zv.x += sc*a0; zv.y += sc*a1; zv.z += sc*a2; zv.w += sc*a3;
    *(float4*)zp = zv;
}

// ---------- vr[row] = rsd[row] * v[row], bf16-compressed
__global__ __launch_bounds__(256) void k_vr(const float* __restrict__ vbuf,
                      const float* __restrict__ rsd, unsigned short* __restrict__ vr) {
    int t = threadIdx.x;
    int row = blockIdx.x*4 + (t >> 6);
    int lane = t & 63;
    float rs = rsd[row];
    float4 v4 = *(const float4*)(vbuf + (size_t)row*256 + lane*4);
    ushort4 o;
    o.x = f2bf(rs * v4.x);
    o.y = f2bf(rs * v4.y);
    o.z = f2bf(rs * v4.z);
    o.w = f2bf(rs * v4.w);
    *(ushort4*)(vr + (size_t)row*256 + lane*4) = o;
}

// ---------- out[n][o] = sum_f znext[n][f] * Wo[o][f] + Wob[o]
__global__ __launch_bounds__(256) void k_out(const float* __restrict__ znext, const float* __restrict__ WoT,
                      const float* __restrict__ Wob, float* __restrict__ out) {
    int n = blockIdx.x*256 + threadIdx.x;
    if (n >= NN) return;
    float acc[64];
    #pragma unroll
    for (int o = 0; o < 64; ++o) acc[o] = Wob[o];
    const float* zr = znext + (size_t)n*256;
    for (int fc = 0; fc < 64; ++fc) {
        float4 z4 = *(const float4*)(zr + fc*4);
        float zz[4] = {z4.x, z4.y, z4.z, z4.w};
        #pragma unroll
        for (int j = 0; j < 4; ++j) {
            const float* wr = WoT + (fc*4+j)*64;
            #pragma unroll
            for (int o = 0; o < 64; ++o)
                acc[o] = fmaf(zz[j], wr[o], acc[o]);
        }
    }
    float* ob = out + (size_t)n*64;
    #pragma unroll
    for (int o = 0; o < 64; ++o) ob[o] = acc[o];
}

extern "C" void kernel_launch(void* const* d_in, const int* in_sizes, int n_in,
                              void* d_out, int out_size, void* d_ws, size_t ws_size,
                              hipStream_t stream) {
    const float* z    = (const float*)d_in[0];
    const int*   ei   = (const int*)d_in[1];
    const float* Wq   = (const float*)d_in[2];
    const float* Wqb  = (const float*)d_in[3];
    const float* Wk   = (const float*)d_in[4];
    const float* Wkb  = (const float*)d_in[5];
    const float* Wv   = (const float*)d_in[6];
    const float* Wvb  = (const float*)d_in[7];
    const float* Wo   = (const float*)d_in[8];
    const float* Wob  = (const float*)d_in[9];
    const float* brb  = (const float*)d_in[10];
    const float* proj = (const float*)d_in[11];
    const float* g    = (const float*)d_in[12];
    float* out = (float*)d_out;
    float* A   = out + (size_t)NN*64;
    float* ws  = (float*)d_ws;

    float* Wt      = ws;                 // 131072
    float* bext    = ws + 131072;        // 1024
    float* WoT     = ws + 132096;        // 16384
    float* kvs     = ws + 148480;        // 81920
    float* ktg     = ws + 230400;        // 1280
    float* kp_sum  = ws + 231680;        // 128
    unsigned* stab = (unsigned*)(ws + 231808); // 4
    int* din       = (int*)(ws + 231812);      // 50000
    int* dout_     = (int*)(ws + 281812);      // 50000
    float* vbuf    = ws + 331840;        // 12.8M
    float* qp      = ws + 13131840;      // 6.4M
    float* kpb     = ws + 19531840;      // 6.4M (raw dash; dead after k_kp)
    float* znext   = ws + 25931840;      // 12.8M
    int* offsets   = (int*)(ws + 38731840);    // 50001 (pad to 50004)
    int* cursor    = (int*)(ws + 38781844);    // 50000
    int* bsum      = (int*)(ws + 38831844);    // 196
    int* boff      = (int*)(ws + 38832040);    // 196
    float* rsd     = ws + 38832236;            // 50000 -> 38882236
    unsigned short* Wcb = (unsigned short*)(ws + 38882240);      // 262144 ushorts
    unsigned short* kvs_bfT = (unsigned short*)(ws + 39013312);  // 81920 ushorts -> end ~39054272
    // aliases:
    //   vT  (256 x 50176 bf16 = 25.7MB) -> znext region (dead until k_znext_mfma)
    //   csr_pack (800000 int2)          -> kpb region [0 .. 1600000)
    //   A_scratch (3.2M floats)         -> kpb region [1600000 .. 4800000)
    //   vr  (12.8M bf16)                -> qp region (fp32 qp dead after k_znext_mfma)
    //   kp_bf  (6.4M bf16)              -> A segment of d_out
    //   qpn_bf (6.4M bf16)              -> out segment of d_out
    unsigned short* vT     = (unsigned short*)znext;
    int2* csr_pack         = (int2*)kpb;
    float* A_scratch       = kpb + 1600000;
    unsigned short* vr     = (unsigned short*)qp;
    unsigned short* kp_bf  = (unsigned short*)A;
    unsigned short* qpn_bf = (unsigned short*)out;

    hipMemsetAsync(ws + 148480, 0, (size_t)(331840 - 148480)*sizeof(float), stream);
    k_prep<<<128, 256, 0, stream>>>(Wq, Wqb, Wk, Wkb, Wv, Wvb, Wo, proj, Wt, bext, WoT);
    k_prep2<<<512, 256, 0, stream>>>(Wt, Wcb);
    k_ztail<<<88, 256, 0, stream>>>((unsigned*)vT);
    k_qkv_mfma<<<391, 256, 0, stream>>>(z, Wcb, bext, vbuf, qp, kpb, stab);
    k_deg<<<3125, 256, 0, stream>>>(ei, din, dout_);
    k_scan_part<<<196, 256, 0, stream>>>(din, bsum);
    k_scan_top<<<1, 64, 0, stream>>>(bsum, boff);
    k_scan_fin<<<196, 256, 0, stream>>>(din, boff, offsets, cursor, dout_, rsd);
    k_kp<<<512, 256, 0, stream>>>(kpb, stab, kp_sum, kp_bf);      // raw kpb dead after this
    k_scatter<<<3125, 256, 0, stream>>>(ei, cursor, csr_pack);
    k_vt<<<dim3(782, 4), 256, 0, stream>>>(vbuf, vT);
    k_kvs<<<dim3(KVSNB, 4), 256, 0, stream>>>(kp_bf, g, vT, kvs, ktg);
    k_kvsbf<<<320, 256, 0, stream>>>(kvs, kvs_bfT);
    k_znext_mfma<<<dim3(782, 4), 256, 0, stream>>>(qp, kvs_bfT, ktg, kp_sum, znext, qpn_bf);
    k_vr<<<12500, 256, 0, stream>>>(vbuf, rsd, vr);                 // vr aliases qp (dead now)
    k_convedge<<<12500, 256, 0, stream>>>(offsets, csr_pack, din, vr, kp_bf,
                                          qpn_bf, brb, znext, A_scratch);
    k_out<<<196, 256, 0, stream>>>(znext, WoT, Wob, out);
    hipMemcpyAsync(A, A_scratch, (size_t)EE*4*sizeof(float), hipMemcpyDeviceToDevice, stream);
}

// Round 23
// 640.708 us; speedup vs baseline: 1.0487x; 1.0296x over previous
//
#include <hip/hip_runtime.h>

#define NN 50000
#define EE 800000
#define IND 128
#define NCOL 1024
#define KM 320            // K * Mpad = 10*32
#define M30 30
#define RATIO 0.1825741858f   // 30^-0.5
#define EPSF 1e-6f
#define QKSCALE 0.7071067812f // (1/sqrt(0.25)) * 64^-0.25
#define VTS 50176             // vT row stride (196*256)
#define KVSNB 196             // k_kvs node-chunk blocks (256 nodes each)
#define AST 136               // a-tile LDS row stride in bf16 (2-way-free banks)

typedef __attribute__((ext_vector_type(8))) short bf16x8;
typedef __attribute__((ext_vector_type(4))) float f32x4;

__device__ __forceinline__ unsigned f2s(float f) {
    unsigned u = __float_as_uint(f);
    return (u & 0x80000000u) ? ~u : (u | 0x80000000u);
}
__device__ __forceinline__ float s2f(unsigned s) {
    return __uint_as_float((s & 0x80000000u) ? (s & 0x7fffffffu) : ~s);
}
__device__ __forceinline__ unsigned short f2bf(float f) {   // RTNE fp32->bf16
    unsigned u = __float_as_uint(f);
    unsigned r = u + 0x7fffu + ((u >> 16) & 1u);
    return (unsigned short)(r >> 16);
}
__device__ __forceinline__ float bf2f(unsigned short h) {
    return __uint_as_float(((unsigned)h) << 16);
}

// ---------- prep: Wt[IND][NCOL] (cols: 0-255 s*Wq^T, 256-511 s*Wk^T, 512-767 Wv^T,
// 768-895 Pq[h,m], 896-1023 Pk[h,m]), bias_ext[NCOL], WoT[256][64]
__global__ void k_prep(const float* __restrict__ Wq, const float* __restrict__ Wqb,
                       const float* __restrict__ Wk, const float* __restrict__ Wkb,
                       const float* __restrict__ Wv, const float* __restrict__ Wvb,
                       const float* __restrict__ Wo, const float* __restrict__ proj,
                       float* __restrict__ Wt, float* __restrict__ bext, float* __restrict__ WoT) {
    int i = blockIdx.x;   // 0..127
    int t = threadIdx.x;  // 0..255
    Wt[i*NCOL + t]       = QKSCALE * Wq[t*IND + i];
    Wt[i*NCOL + 256 + t] = QKSCALE * Wk[t*IND + i];
    Wt[i*NCOL + 512 + t] = Wv[t*IND + i];
    {
        const float* W = (t < 128) ? Wq : Wk;
        int c = (t < 128) ? t : (t - 128);
        int h = c >> 5, m = c & 31;
        float val = 0.f;
        if (m < M30) {
            for (int d = 0; d < 64; ++d)
                val += QKSCALE * W[(h*64+d)*IND + i] * proj[m*64 + d];
        }
        Wt[i*NCOL + 768 + t] = val;
    }
    if (t < 128) {
        int f = i*2 + (t >> 6);
        int o = t & 63;
        WoT[f*64 + o] = Wo[o*256 + f];
    }
    if (i == 0) {
        bext[t]       = QKSCALE * Wqb[t];
        bext[256 + t] = QKSCALE * Wkb[t];
        bext[512 + t] = Wvb[t];
        const float* Bb = (t < 128) ? Wqb : Wkb;
        int c = (t < 128) ? t : (t - 128);
        int h = c >> 5, m = c & 31;
        float val = 0.f;
        if (m < M30) {
            for (int d = 0; d < 64; ++d)
                val += QKSCALE * Bb[h*64+d] * proj[m*64 + d];
        }
        bext[768 + t] = val;
    }
}

// ---------- Wcb: bf16 hi/lo split of Wt, layout [col][k] (MFMA B operand)
__global__ void k_prep2(const float* __restrict__ Wt, unsigned short* __restrict__ Wcb) {
    int idx = blockIdx.x*256 + threadIdx.x;   // 512 blocks -> 131072
    int col = idx >> 7, k = idx & 127;
    float f = Wt[k*NCOL + col];
    unsigned short hi = f2bf(f);
    unsigned short lo = f2bf(f - bf2f(hi));
    Wcb[col*128 + k] = hi;
    Wcb[131072 + col*128 + k] = lo;
}

// ---------- zero vT tail cols [50000,50176) (vT aliases znext; replay determinism)
__global__ void k_ztail(unsigned* __restrict__ vT32) {
    int idx = blockIdx.x*256 + threadIdx.x;  // 88 blocks * 256 = 22528 = 256*88
    int row = idx / 88, c = idx - row*88;
    vT32[(size_t)row * (VTS/2) + (50000/2) + c] = 0u;
}

// ---------- fused QKV+dash GEMM via bf16x2 MFMA (A single-rounded, B hi+lo).
// ROUND-23: 128 nodes/block, nt SPLIT INTO OUTER 2-HALF LOOP: live acc[8][2]=64
// VGPR (was acc[8][4]=128 which spilled at the 256 ISA cap, WRITE 168MB).
// Each B hi/lo pair still feeds 8mt x 2 = 16 MFMAs (the latency-cover property);
// A re-read per half comes from LDS (cheap). diag accumulated via dsum partials;
// c==3 epilogue's p index == half index, so it decomposes exactly.
__global__ __launch_bounds__(256) void k_qkv_mfma(const float* __restrict__ z,
                      const unsigned short* __restrict__ Wcb, const float* __restrict__ bext,
                      float* __restrict__ vbuf, float* __restrict__ qp, float* __restrict__ kpb,
                      unsigned* __restrict__ stab) {
    __shared__ __align__(16) unsigned short a_hi[128*AST];
    __shared__ float diag_l[2][4][128];   // [q/k][head][node]
    int t = threadIdx.x;
    int n0 = blockIdx.x * 128;
    int w = t >> 6, lane = t & 63;
    #pragma unroll
    for (int half = 0; half < 2; ++half) {
        int node = (t >> 2) + half*64;
        int ks = (t & 3) * 32;
        bool ok = (n0 + node) < NN;
        const float* zr = z + (size_t)(n0 + node)*IND + ks;
        unsigned hbuf[16];
        #pragma unroll
        for (int c = 0; c < 8; ++c) {
            float4 v = ok ? *(const float4*)(zr + c*4) : make_float4(0.f,0.f,0.f,0.f);
            hbuf[c*2]   = (unsigned)f2bf(v.x) | ((unsigned)f2bf(v.y) << 16);
            hbuf[c*2+1] = (unsigned)f2bf(v.z) | ((unsigned)f2bf(v.w) << 16);
        }
        uint4* hp = (uint4*)(&a_hi[node*AST + ks]);
        #pragma unroll
        for (int c = 0; c < 4; ++c)
            hp[c] = make_uint4(hbuf[c*4], hbuf[c*4+1], hbuf[c*4+2], hbuf[c*4+3]);
    }
    __syncthreads();
    int arow = lane & 15;
    int ao = (lane >> 4) * 8;
    for (int c = 0; c < 4; ++c) {
        int colbase = c*256 + w*64;
        float dsum[8][4];                 // diag partials (live only for c<2)
        if (c < 2) {
            #pragma unroll
            for (int mt = 0; mt < 8; ++mt)
                #pragma unroll
                for (int r = 0; r < 4; ++r) dsum[mt][r] = 0.f;
        }
        #pragma unroll
        for (int half = 0; half < 2; ++half) {
            f32x4 acc[8][2];
            #pragma unroll
            for (int mt = 0; mt < 8; ++mt)
                #pragma unroll
                for (int ntl = 0; ntl < 2; ++ntl)
                    acc[mt][ntl] = (f32x4){0.f,0.f,0.f,0.f};
            #pragma unroll
            for (int ks = 0; ks < 4; ++ks) {
                int ko = ks*32 + ao;
                bf16x8 Ah[8];
                #pragma unroll
                for (int mt = 0; mt < 8; ++mt)
                    Ah[mt] = *(const bf16x8*)(&a_hi[(mt*16 + arow)*AST + ko]);
                #pragma unroll
                for (int ntl = 0; ntl < 2; ++ntl) {
                    int nt = half*2 + ntl;
                    const unsigned short* bp = Wcb + (size_t)(colbase + nt*16 + arow)*128 + ko;
                    bf16x8 Bh = *(const bf16x8*)bp;
                    bf16x8 Bl = *(const bf16x8*)(bp + 131072);
                    #pragma unroll
                    for (int mt = 0; mt < 8; ++mt) {
                        acc[mt][ntl] = __builtin_amdgcn_mfma_f32_16x16x32_bf16(Ah[mt], Bh, acc[mt][ntl], 0, 0, 0);
                        acc[mt][ntl] = __builtin_amdgcn_mfma_f32_16x16x32_bf16(Ah[mt], Bl, acc[mt][ntl], 0, 0, 0);
                    }
                }
            }
            // bias (per col)
            float bv[2];
            #pragma unroll
            for (int ntl = 0; ntl < 2; ++ntl)
                bv[ntl] = bext[colbase + (half*2 + ntl)*16 + arow];
            #pragma unroll
            for (int mt = 0; mt < 8; ++mt)
                #pragma unroll
                for (int ntl = 0; ntl < 2; ++ntl)
                    #pragma unroll
                    for (int r = 0; r < 4; ++r)
                        acc[mt][ntl][r] += bv[ntl];
            // D layout: row = 16mt + (lane>>4)*4 + r, col = 16*(half*2+ntl) + (lane&15)
            if (c < 2) {
                #pragma unroll
                for (int mt = 0; mt < 8; ++mt)
                    #pragma unroll
                    for (int r = 0; r < 4; ++r)
                        dsum[mt][r] += acc[mt][0][r]*acc[mt][0][r] + acc[mt][1][r]*acc[mt][1][r];
            } else if (c == 2) {
                #pragma unroll
                for (int mt = 0; mt < 8; ++mt)
                    #pragma unroll
                    for (int r = 0; r < 4; ++r) {
                        int node = n0 + mt*16 + (lane>>4)*4 + r;
                        if (node < NN) {
                            #pragma unroll
                            for (int ntl = 0; ntl < 2; ++ntl)
                                vbuf[(size_t)node*256 + w*64 + (half*2+ntl)*16 + arow] = acc[mt][ntl][r];
                        }
                    }
            } else {
                int hh = (w & 1) * 2;
                int p = half;            // nt pair {2p, 2p+1} == this half
                int h = hh + p;
                if (w < 2) {
                    // q-dash -> qp
                    #pragma unroll
                    for (int mt = 0; mt < 8; ++mt) {
                        #pragma unroll
                        for (int r = 0; r < 4; ++r) {
                            int row = mt*16 + (lane>>4)*4 + r;
                            float dg = diag_l[0][h][row];
                            float mx = fmaxf(acc[mt][0][r],
                                             (arow < 14) ? acc[mt][1][r] : -3.0e38f);
                            mx = fmaxf(mx, __shfl_xor(mx, 1)); mx = fmaxf(mx, __shfl_xor(mx, 2));
                            mx = fmaxf(mx, __shfl_xor(mx, 4)); mx = fmaxf(mx, __shfl_xor(mx, 8));
                            int node = n0 + row;
                            if (node < NN) {
                                #pragma unroll
                                for (int q2 = 0; q2 < 2; ++q2) {
                                    int m = q2*16 + arow;
                                    float val = 0.f;
                                    if (m < M30)
                                        val = RATIO * (__expf(acc[mt][q2][r] - dg - mx) + EPSF);
                                    qp[(size_t)node*128 + h*32 + m] = val;
                                }
                            }
                        }
                    }
                } else {
                    // k-dash -> kpb raw + stab
                    float smax = -3.0e38f;
                    #pragma unroll
                    for (int mt = 0; mt < 8; ++mt) {
                        #pragma unroll
                        for (int r = 0; r < 4; ++r) {
                            int row = mt*16 + (lane>>4)*4 + r;
                            float dg = diag_l[1][h][row];
                            int node = n0 + row;
                            if (node < NN) {
                                #pragma unroll
                                for (int q2 = 0; q2 < 2; ++q2) {
                                    int m = q2*16 + arow;
                                    float d = acc[mt][q2][r];
                                    bool valid = (m < M30);
                                    kpb[(size_t)node*128 + h*32 + m] = valid ? (d - dg) : 0.f;
                                    if (valid) smax = fmaxf(smax, d);
                                }
                            }
                        }
                    }
                    smax = fmaxf(smax, __shfl_xor(smax, 1));  smax = fmaxf(smax, __shfl_xor(smax, 2));
                    smax = fmaxf(smax, __shfl_xor(smax, 4));  smax = fmaxf(smax, __shfl_xor(smax, 8));
                    smax = fmaxf(smax, __shfl_xor(smax, 16)); smax = fmaxf(smax, __shfl_xor(smax, 32));
                    if (lane == 0) atomicMax(&stab[h], f2s(smax));
                }
            }
        }
        if (c < 2) {
            // finish diag: sum over the 16 arow lanes, write per-head slice
            #pragma unroll
            for (int mt = 0; mt < 8; ++mt) {
                #pragma unroll
                for (int r = 0; r < 4; ++r) {
                    float s = dsum[mt][r];
                    s += __shfl_xor(s, 1); s += __shfl_xor(s, 2);
                    s += __shfl_xor(s, 4); s += __shfl_xor(s, 8);
                    if (arow == 0) diag_l[c][w][mt*16 + (lane>>4)*4 + r] = 0.5f*s;
                }
            }
        }
        __syncthreads();
    }
}

// ---------- vT[c][n] = bf16(vbuf[n][c]) tiled transpose (64x64 tiles via LDS)
__global__ __launch_bounds__(256) void k_vt(const float* __restrict__ vbuf,
                      unsigned short* __restrict__ vT) {
    __shared__ unsigned short tile[64][72];
    int t = threadIdx.x;
    int n0 = blockIdx.x * 64;
    int c0 = blockIdx.y * 64;
    {
        int node = t >> 2, cs = (t & 3) * 16;
        bool ok = (n0 + node) < NN;
        const float* vr = vbuf + (size_t)(n0 + node)*256 + c0 + cs;
        #pragma unroll
        for (int cc = 0; cc < 4; ++cc) {
            float4 v = ok ? *(const float4*)(vr + cc*4) : make_float4(0.f,0.f,0.f,0.f);
            unsigned u0 = (unsigned)f2bf(v.x) | ((unsigned)f2bf(v.y) << 16);
            unsigned u1 = (unsigned)f2bf(v.z) | ((unsigned)f2bf(v.w) << 16);
            *(unsigned*)(&tile[node][cs + cc*4])     = u0;
            *(unsigned*)(&tile[node][cs + cc*4 + 2]) = u1;
        }
    }
    __syncthreads();
    {
        int d = t >> 2, ns = (t & 3) * 16;
        unsigned ob[8];
        #pragma unroll
        for (int i = 0; i < 8; ++i) {
            unsigned short a = tile[ns + i*2][d];
            unsigned short b = tile[ns + i*2 + 1][d];
            ob[i] = (unsigned)a | ((unsigned)b << 16);
        }
        unsigned short* op = vT + (size_t)(c0 + d)*VTS + n0 + ns;
        *(uint4*)(op)     = make_uint4(ob[0], ob[1], ob[2], ob[3]);
        *(uint4*)(op + 8) = make_uint4(ob[4], ob[5], ob[6], ob[7]);
    }
}

__global__ void k_deg(const int* __restrict__ ei, int* __restrict__ din, int* __restrict__ dout) {
    int e = blockIdx.x*256 + threadIdx.x;
    if (e < EE) {
        atomicAdd(&dout[ei[e]], 1);
        atomicAdd(&din[ei[EE + e]], 1);
    }
}

// ---------- prefix sum over din (3-kernel scan) ----------
__global__ void k_scan_part(const int* __restrict__ din, int* __restrict__ bsum) {
    __shared__ int red[256];
    int t = threadIdx.x;
    int i = blockIdx.x*256 + t;
    red[t] = (i < NN) ? din[i] : 0;
    __syncthreads();
    for (int off = 128; off >= 1; off >>= 1) {
        if (t < off) red[t] += red[t+off];
        __syncthreads();
    }
    if (t == 0) bsum[blockIdx.x] = red[0];
}
__global__ void k_scan_top(const int* __restrict__ bsum, int* __restrict__ boff) {
    if (threadIdx.x == 0) {
        int acc = 0;
        for (int b = 0; b < 196; ++b) { boff[b] = acc; acc += bsum[b]; }
    }
}
// scan finish + rsd = rsqrt(dout) (k_rs folded in)
__global__ void k_scan_fin(const int* __restrict__ din, const int* __restrict__ boff,
                           int* __restrict__ offsets, int* __restrict__ cursor,
                           const int* __restrict__ dout_, float* __restrict__ rsd) {
    __shared__ int s[256];
    int t = threadIdx.x;
    int i = blockIdx.x*256 + t;
    if (i < NN) {
        int d = dout_[i];
        rsd[i] = d > 0 ? rsqrtf((float)d) : 0.f;
    }
    int v = (i < NN) ? din[i] : 0;
    s[t] = v;
    __syncthreads();
    for (int off = 1; off < 256; off <<= 1) {
        int add = (t >= off) ? s[t-off] : 0;
        __syncthreads();
        s[t] += add;
        __syncthreads();
    }
    int excl = s[t] - v + boff[blockIdx.x];
    if (i < NN) { offsets[i] = excl; cursor[i] = excl; }
    if (i == NN-1) offsets[NN] = excl + v;
}

// scatter (row, eid) packed as int2 into CSR-by-col order
__global__ void k_scatter(const int* __restrict__ ei, int* __restrict__ cursor,
                          int2* __restrict__ csr_pack) {
    int e = blockIdx.x*256 + threadIdx.x;
    if (e < EE) {
        int col = ei[EE + e];
        int pos = atomicAdd(&cursor[col], 1);
        csr_pack[pos] = make_int2(ei[e], e);
    }
}

// ---------- finish kp = ratio*(exp(dash-diag-stab)+eps) -> kp_bf (bf16); kp_sum[h][m]
__global__ void k_kp(const float* __restrict__ kpb, const unsigned* __restrict__ stab,
                     float* __restrict__ kp_sum, unsigned short* __restrict__ kp_bf) {
    __shared__ float red[256];
    int t = threadIdx.x;
    int hm = t & 127;
    int h = hm >> 5, m = hm & 31;
    float st = s2f(stab[h]);
    float ksum = 0.f;
    const int total = NN*128;
    for (int idx = blockIdx.x*256 + t; idx < total; idx += gridDim.x*256) {
        float val = kpb[idx];
        float kpv = 0.f;
        if (m < M30) kpv = RATIO * (__expf(val - st) + EPSF);
        kp_bf[idx] = f2bf(kpv);
        ksum += kpv;
    }
    red[t] = ksum;
    __syncthreads();
    if (t < 128) atomicAdd(&kp_sum[hm], red[t] + red[t+128]);
}

// ---------- kvs[h][km][d] = sum_n w[n,km]*v[n,d] via MFMA (16x16x32 bf16).
__global__ __launch_bounds__(256) void k_kvs(const unsigned short* __restrict__ kp_bf,
                      const float* __restrict__ g, const unsigned short* __restrict__ vT,
                      float* __restrict__ kvs, float* __restrict__ ktg) {
    __shared__ __align__(16) unsigned short w_l[320*40]; // row stride 40 bf16 (80B)
    __shared__ __align__(16) unsigned short v_l[64*40];
    __shared__ __align__(16) float eg_l[10][36];
    __shared__ float kp_lf[32][33];                      // 32 nodes x 32 m (pad 33)
    int t = threadIdx.x;
    int h = blockIdx.y;
    int n0b = blockIdx.x * 256;
    int lane = t & 63;
    int wb = (t >> 6) * 80;            // wave's km base
    int arow = lane & 15;
    int acol = (lane >> 4) * 8;        // bf16 col offset of the 8-elem fragment
    f32x4 acc[5][4];
    #pragma unroll
    for (int kt = 0; kt < 5; ++kt)
        #pragma unroll
        for (int dt = 0; dt < 4; ++dt)
            acc[kt][dt] = (f32x4){0.f, 0.f, 0.f, 0.f};
    float wsum0 = 0.f, wsum1 = 0.f;
    int k0 = t >> 5, m0 = t & 31;      // row t = k0*32 + m0
    int k1 = 8 + (t >> 5), m1 = t & 31; // row t+256 (t<64)

    for (int st = 0; st < 8; ++st) {
        int n0 = n0b + st * 32;
        __syncthreads();               // prev tile consumed by MFMA
        #pragma unroll
        for (int i = 0; i < 2; ++i) {
            int flat = t + i*256;
            if (flat < 320) {
                int kk = flat % 10, n = flat / 10;
                float e = 0.f;
                if (n0 + n < NN) e = __expf(g[(size_t)(n0+n)*40 + h*10 + kk]);
                eg_l[kk][n] = e;
            }
        }
        {
            int d = t >> 2, seg = t & 3;
            uint4 vv = *(const uint4*)(vT + (size_t)(h*64 + d)*VTS + n0 + seg*8);
            *(uint4*)(&v_l[d*40 + seg*8]) = vv;
        }
        if (t < 128) {
            int n = t >> 2, seg = t & 3;
            int gn = n0 + n;
            if (gn < NN) {
                uint4 kv = *(const uint4*)(kp_bf + (size_t)gn*128 + h*32 + seg*8);
                unsigned uu[4] = {kv.x, kv.y, kv.z, kv.w};
                #pragma unroll
                for (int j = 0; j < 4; ++j) {
                    kp_lf[n][seg*8 + j*2]     = __uint_as_float(uu[j] << 16);
                    kp_lf[n][seg*8 + j*2 + 1] = __uint_as_float(uu[j] & 0xFFFF0000u);
                }
            } else {
                #pragma unroll
                for (int j = 0; j < 8; ++j) kp_lf[n][seg*8 + j] = 0.f;
            }
        }
        __syncthreads();
        {
            // row t
            {
                unsigned dw[16];
                float s = 0.f;
                #pragma unroll
                for (int c = 0; c < 16; ++c) {
                    float kpa = kp_lf[c*2][m0];
                    float kpc = kp_lf[c*2+1][m0];
                    unsigned ua = __float_as_uint(kpa * eg_l[k0][c*2]);
                    unsigned ub = __float_as_uint(kpc * eg_l[k0][c*2+1]);
                    s += __uint_as_float(ua & 0xFFFF0000u) + __uint_as_float(ub & 0xFFFF0000u);
                    dw[c] = (ua >> 16) | (ub & 0xFFFF0000u);
                }
                wsum0 += s;
                uint4* wp = (uint4*)(&w_l[t*40]);
                wp[0] = make_uint4(dw[0], dw[1], dw[2],  dw[3]);
                wp[1] = make_uint4(dw[4], dw[5], dw[6],  dw[7]);
                wp[2] = make_uint4(dw[8], dw[9], dw[10], dw[11]);
                wp[3] = make_uint4(dw[12],dw[13],dw[14], dw[15]);
            }
            if (t < 64) {
                unsigned dw[16];
                float s = 0.f;
                #pragma unroll
                for (int c = 0; c < 16; ++c) {
                    float kpa = kp_lf[c*2][m1];
                    float kpc = kp_lf[c*2+1][m1];
                    unsigned ua = __float_as_uint(kpa * eg_l[k1][c*2]);
                    unsigned ub = __float_as_uint(kpc * eg_l[k1][c*2+1]);
                    s += __uint_as_float(ua & 0xFFFF0000u) + __uint_as_float(ub & 0xFFFF0000u);
                    dw[c] = (ua >> 16) | (ub & 0xFFFF0000u);
                }
                wsum1 += s;
                uint4* wp = (uint4*)(&w_l[(t + 256)*40]);
                wp[0] = make_uint4(dw[0], dw[1], dw[2],  dw[3]);
                wp[1] = make_uint4(dw[4], dw[5], dw[6],  dw[7]);
                wp[2] = make_uint4(dw[8], dw[9], dw[10], dw[11]);
                wp[3] = make_uint4(dw[12],dw[13],dw[14], dw[15]);
            }
        }
        __syncthreads();
        bf16x8 Bf[4];
        #pragma unroll
        for (int dt = 0; dt < 4; ++dt)
            Bf[dt] = *(const bf16x8*)(&v_l[(dt*16 + arow)*40 + acol]);
        #pragma unroll
        for (int kt = 0; kt < 5; ++kt) {
            bf16x8 Af = *(const bf16x8*)(&w_l[(wb + kt*16 + arow)*40 + acol]);
            #pragma unroll
            for (int dt = 0; dt < 4; ++dt)
                acc[kt][dt] = __builtin_amdgcn_mfma_f32_16x16x32_bf16(Af, Bf[dt], acc[kt][dt], 0, 0, 0);
        }
    }
    {
        int orow = (lane >> 4) * 4;
        int ocol = lane & 15;
        float* kb = kvs + h*KM*64;
        #pragma unroll
        for (int kt = 0; kt < 5; ++kt)
            #pragma unroll
            for (int dt = 0; dt < 4; ++dt)
                #pragma unroll
                for (int r = 0; r < 4; ++r)
                    atomicAdd(&kb[(wb + kt*16 + orow + r)*64 + dt*16 + ocol], acc[kt][dt][r]);
        atomicAdd(&ktg[h*KM + t], wsum0);
        if (t < 64) atomicAdd(&ktg[h*KM + 256 + t], wsum1);
    }
}

// ---------- kvs_bfT[h][d][km] = bf16(kvs[h][km][d])  (B operand for k_znext_mfma)
__global__ void k_kvsbf(const float* __restrict__ kvs, unsigned short* __restrict__ kvs_bfT) {
    int idx = blockIdx.x*256 + threadIdx.x;   // 320 blocks -> 81920 exact
    int h = idx / 20480;
    int rem = idx - h*20480;
    int d = rem / 320;
    int km = rem - d*320;
    kvs_bfT[idx] = f2bf(kvs[(size_t)h*20480 + km*64 + d]);
}

// ---------- znext via MFMA: A[n][k*32+m] = qpn[n][m]*rd[n][k] (bf16, LDS),
// B = kvs_bfT[h][d][km]. D[n][d] = znext. Also emits qpn_bf.
__global__ __launch_bounds__(256) void k_znext_mfma(const float* __restrict__ qp,
                        const unsigned short* __restrict__ kvs_bfT,
                        const float* __restrict__ ktg, const float* __restrict__ kp_sum,
                        float* __restrict__ znext, unsigned short* __restrict__ qpn_bf) {
    __shared__ __align__(16) unsigned short A_l[64*328];
    __shared__ float ktg_l[320];
    __shared__ float ksum_l[32];
    int t = threadIdx.x;
    int h = blockIdx.y;
    int n0 = blockIdx.x * 64;
    ktg_l[t] = ktg[h*KM + t];
    if (t < 64) ktg_l[256 + t] = ktg[h*KM + 256 + t];
    if (t < 32) ksum_l[t] = kp_sum[h*32 + t];
    __syncthreads();
    // ---- phase 1: thread = node*4 + p; p owns m in [p*8, p*8+8)
    {
        int node = t >> 2, p = t & 3;
        int n = n0 + node;
        bool ok = (n < NN);
        float q8[8];
        if (ok) {
            const float* qb = qp + (size_t)n*128 + h*32 + p*8;
            float4 a = *(const float4*)(qb);
            float4 b = *(const float4*)(qb + 4);
            q8[0]=a.x; q8[1]=a.y; q8[2]=a.z; q8[3]=a.w;
            q8[4]=b.x; q8[5]=b.y; q8[6]=b.z; q8[7]=b.w;
        } else {
            #pragma unroll
            for (int j = 0; j < 8; ++j) q8[j] = 0.f;
        }
        float part = 0.f;
        #pragma unroll
        for (int j = 0; j < 8; ++j) part = fmaf(q8[j], ksum_l[p*8 + j], part);
        part += __shfl_xor(part, 1); part += __shfl_xor(part, 2);
        float rn = ok ? (1.f / part) : 0.f;
        #pragma unroll
        for (int j = 0; j < 8; ++j) q8[j] *= rn;
        if (ok) {
            unsigned ob[4];
            #pragma unroll
            for (int c = 0; c < 4; ++c)
                ob[c] = (unsigned)f2bf(q8[c*2]) | ((unsigned)f2bf(q8[c*2+1]) << 16);
            *(uint4*)(qpn_bf + (size_t)n*128 + h*32 + p*8) = make_uint4(ob[0], ob[1], ob[2], ob[3]);
        }
        #pragma unroll
        for (int k = 0; k < 10; ++k) {
            float dp = 0.f;
            #pragma unroll
            for (int j = 0; j < 8; ++j) dp = fmaf(q8[j], ktg_l[k*32 + p*8 + j], dp);
            dp += __shfl_xor(dp, 1); dp += __shfl_xor(dp, 2);
            float rd = ok ? (1.f / (dp * 10.f)) : 0.f;
            unsigned ob[4];
            #pragma unroll
            for (int c = 0; c < 4; ++c)
                ob[c] = (unsigned)f2bf(q8[c*2]*rd) | ((unsigned)f2bf(q8[c*2+1]*rd) << 16);
            *(uint4*)(&A_l[node*328 + k*32 + p*8]) = make_uint4(ob[0], ob[1], ob[2], ob[3]);
        }
    }
    __syncthreads();
    // ---- phase 2: wave w = 16-d N-tile; 4 M-tiles; 10 K-steps
    {
        int lane = t & 63, w = t >> 6;
        int arow = lane & 15;
        int ao = (lane >> 4) * 8;
        f32x4 acc[4];
        #pragma unroll
        for (int mt = 0; mt < 4; ++mt) acc[mt] = (f32x4){0.f,0.f,0.f,0.f};
        const unsigned short* Bb = kvs_bfT + (size_t)h*20480 + (w*16 + arow)*320;
        #pragma unroll
        for (int ks = 0; ks < 10; ++ks) {
            bf16x8 Bf = *(const bf16x8*)(Bb + ks*32 + ao);
            #pragma unroll
            for (int mt = 0; mt < 4; ++mt) {
                bf16x8 Af = *(const bf16x8*)(&A_l[(mt*16 + arow)*328 + ks*32 + ao]);
                acc[mt] = __builtin_amdgcn_mfma_f32_16x16x32_bf16(Af, Bf, acc[mt], 0, 0, 0);
            }
        }
        #pragma unroll
        for (int mt = 0; mt < 4; ++mt)
            #pragma unroll
            for (int r = 0; r < 4; ++r) {
                int n = n0 + mt*16 + (lane>>4)*4 + r;
                if (n < NN)
                    znext[(size_t)n*256 + h*64 + w*16 + arow] = acc[mt][r];
            }
    }
}

// ---------- FUSED conv + edge over CSR, 2-edge unrolled.
__global__ __launch_bounds__(256) void k_convedge(const int* __restrict__ offsets,
                        const int2* __restrict__ csr_pack,
                        const int* __restrict__ din, const unsigned short* __restrict__ vr,
                        const unsigned short* __restrict__ kp_bf,
                        const unsigned short* __restrict__ qpn_bf,
                        const float* __restrict__ brb, float* __restrict__ znext,
                        float* __restrict__ A) {
    __shared__ unsigned short qpn_l[4][128];
    int t = threadIdx.x;
    int w = t >> 6, lane = t & 63;
    int col = blockIdx.x*4 + w;          // grid exact: col < NN always
    if (lane < 8) {
        uint4 q4 = *(const uint4*)(qpn_bf + (size_t)col*128 + lane*8);
        *(uint4*)(&qpn_l[w][lane*8]) = q4;
    }
    __syncthreads();
    int s0 = offsets[col], s1 = offsets[col+1];
    int hq = (lane & 31) >> 3;
    float qv0, qv1, qv2, qv3;
    {
        ushort4 qq = *(const ushort4*)(&qpn_l[w][hq*32 + (lane & 7)*4]);
        qv0 = bf2f(qq.x); qv1 = bf2f(qq.y); qv2 = bf2f(qq.z); qv3 = bf2f(qq.w);
    }
    bool dowrite = (lane < 32) && ((lane & 7) == 0);
    float a0 = 0.f, a1 = 0.f, a2 = 0.f, a3 = 0.f;
    int j = s0;
    for (; j + 2 <= s1; j += 2) {
        int2 p0 = csr_pack[j];
        int2 p1 = csr_pack[j+1];
        ushort4 u0 = *(const ushort4*)(vr + (size_t)p0.x*256 + lane*4);
        ushort4 u1 = *(const ushort4*)(vr + (size_t)p1.x*256 + lane*4);
        ushort4 k0 = *(const ushort4*)(kp_bf + (size_t)p0.x*128 + (lane & 31)*4);
        ushort4 k1 = *(const ushort4*)(kp_bf + (size_t)p1.x*128 + (lane & 31)*4);
        a0 += bf2f(u0.x) + bf2f(u1.x);
        a1 += bf2f(u0.y) + bf2f(u1.y);
        a2 += bf2f(u0.z) + bf2f(u1.z);
        a3 += bf2f(u0.w) + bf2f(u1.w);
        float d0 = qv0*bf2f(k0.x) + qv1*bf2f(k0.y) + qv2*bf2f(k0.z) + qv3*bf2f(k0.w);
        float d1 = qv0*bf2f(k1.x) + qv1*bf2f(k1.y) + qv2*bf2f(k1.z) + qv3*bf2f(k1.w);
        d0 += __shfl_xor(d0, 1); d1 += __shfl_xor(d1, 1);
        d0 += __shfl_xor(d0, 2); d1 += __shfl_xor(d1, 2);
        d0 += __shfl_xor(d0, 4); d1 += __shfl_xor(d1, 4);
        if (dowrite) {
            A[(size_t)p0.y*4 + hq] = d0;
            A[(size_t)p1.y*4 + hq] = d1;
        }
    }
    if (j < s1) {
        int2 p0 = csr_pack[j];
        ushort4 u0 = *(const ushort4*)(vr + (size_t)p0.x*256 + lane*4);
        ushort4 k0 = *(const ushort4*)(kp_bf + (size_t)p0.x*128 + (lane & 31)*4);
        a0 += bf2f(u0.x); a1 += bf2f(u0.y); a2 += bf2f(u0.z); a3 += bf2f(u0.w);
        float d0 = qv0*bf2f(k0.x) + qv1*bf2f(k0.y) + qv2*bf2f(k0.z) + qv3*bf2f(k0.w);
        d0 += __shfl_xor(d0, 1); d0 += __shfl_xor(d0, 2); d0 += __shfl_xor(d0, 4);
        if (dowrite) A[(size_t)p0.y*4 + hq] = d0;
    }
    if (s0 == s1) return;
    int h = lane >> 4;
    float sig = 1.f / (1.f + __expf(-brb[h]));
    float sc = sig * rsqrtf((float)din[col]);
    float* zp = znext + (size_t)col*256 + lane*4;
    float4 zv = *(float4*)zp;
    zv.x += sc*a0; zv.y += sc*a1; zv.z += sc*a2; zv.w += sc*a3;
    *(float4*)zp = zv;
}

// ---------- vr[row] = rsd[row] * v[row], bf16-compressed
__global__ __launch_bounds__(256) void k_vr(const float* __restrict__ vbuf,
                      const float* __restrict__ rsd, unsigned short* __restrict__ vr) {
    int t = threadIdx.x;
    int row = blockIdx.x*4 + (t >> 6);
    int lane = t & 63;
    float rs = rsd[row];
    float4 v4 = *(const float4*)(vbuf + (size_t)row*256 + lane*4);
    ushort4 o;
    o.x = f2bf(rs * v4.x);
    o.y = f2bf(rs * v4.y);
    o.z = f2bf(rs * v4.z);
    o.w = f2bf(rs * v4.w);
    *(ushort4*)(vr + (size_t)row*256 + lane*4) = o;
}

// ---------- out[n][o] = sum_f znext[n][f] * Wo[o][f] + Wob[o]
__global__ __launch_bounds__(256) void k_out(const float* __restrict__ znext, const float* __restrict__ WoT,
                      const float* __restrict__ Wob, float* __restrict__ out) {
    int n = blockIdx.x*256 + threadIdx.x;
    if (n >= NN) return;
    float acc[64];
    #pragma unroll
    for (int o = 0; o < 64; ++o) acc[o] = Wob[o];
    const float* zr = znext + (size_t)n*256;
    for (int fc = 0; fc < 64; ++fc) {
        float4 z4 = *(const float4*)(zr + fc*4);
        float zz[4] = {z4.x, z4.y, z4.z, z4.w};
        #pragma unroll
        for (int j = 0; j < 4; ++j) {
            const float* wr = WoT + (fc*4+j)*64;
            #pragma unroll
            for (int o = 0; o < 64; ++o)
                acc[o] = fmaf(zz[j], wr[o], acc[o]);
        }
    }
    float* ob = out + (size_t)n*64;
    #pragma unroll
    for (int o = 0; o < 64; ++o) ob[o] = acc[o];
}

extern "C" void kernel_launch(void* const* d_in, const int* in_sizes, int n_in,
                              void* d_out, int out_size, void* d_ws, size_t ws_size,
                              hipStream_t stream) {
    const float* z    = (const float*)d_in[0];
    const int*   ei   = (const int*)d_in[1];
    const float* Wq   = (const float*)d_in[2];
    const float* Wqb  = (const float*)d_in[3];
    const float* Wk   = (const float*)d_in[4];
    const float* Wkb  = (const float*)d_in[5];
    const float* Wv   = (const float*)d_in[6];
    const float* Wvb  = (const float*)d_in[7];
    const float* Wo   = (const float*)d_in[8];
    const float* Wob  = (const float*)d_in[9];
    const float* brb  = (const float*)d_in[10];
    const float* proj = (const float*)d_in[11];
    const float* g    = (const float*)d_in[12];
    float* out = (float*)d_out;
    float* A   = out + (size_t)NN*64;
    float* ws  = (float*)d_ws;

    float* Wt      = ws;                 // 131072
    float* bext    = ws + 131072;        // 1024
    float* WoT     = ws + 132096;        // 16384
    float* kvs     = ws + 148480;        // 81920
    float* ktg     = ws + 230400;        // 1280
    float* kp_sum  = ws + 231680;        // 128
    unsigned* stab = (unsigned*)(ws + 231808); // 4
    int* din       = (int*)(ws + 231812);      // 50000
    int* dout_     = (int*)(ws + 281812);      // 50000
    float* vbuf    = ws + 331840;        // 12.8M
    float* qp      = ws + 13131840;      // 6.4M
    float* kpb     = ws + 19531840;      // 6.4M (raw dash; dead after k_kp)
    float* znext   = ws + 25931840;      // 12.8M
    int* offsets   = (int*)(ws + 38731840);    // 50001 (pad to 50004)
    int* cursor    = (int*)(ws + 38781844);    // 50000
    int* bsum      = (int*)(ws + 38831844);    // 196
    int* boff      = (int*)(ws + 38832040);    // 196
    float* rsd     = ws + 38832236;            // 50000 -> 38882236
    unsigned short* Wcb = (unsigned short*)(ws + 38882240);      // 262144 ushorts
    unsigned short* kvs_bfT = (unsigned short*)(ws + 39013312);  // 81920 ushorts -> end ~39054272
    // aliases:
    //   vT  (256 x 50176 bf16 = 25.7MB) -> znext region (dead until k_znext_mfma)
    //   csr_pack (800000 int2)          -> kpb region [0 .. 1600000)
    //   A_scratch (3.2M floats)         -> kpb region [1600000 .. 4800000)
    //   vr  (12.8M bf16)                -> qp region (fp32 qp dead after k_znext_mfma)
    //   kp_bf  (6.4M bf16)              -> A segment of d_out
    //   qpn_bf (6.4M bf16)              -> out segment of d_out
    unsigned short* vT     = (unsigned short*)znext;
    int2* csr_pack         = (int2*)kpb;
    float* A_scratch       = kpb + 1600000;
    unsigned short* vr     = (unsigned short*)qp;
    unsigned short* kp_bf  = (unsigned short*)A;
    unsigned short* qpn_bf = (unsigned short*)out;

    hipMemsetAsync(ws + 148480, 0, (size_t)(331840 - 148480)*sizeof(float), stream);
    k_prep<<<128, 256, 0, stream>>>(Wq, Wqb, Wk, Wkb, Wv, Wvb, Wo, proj, Wt, bext, WoT);
    k_prep2<<<512, 256, 0, stream>>>(Wt, Wcb);
    k_ztail<<<88, 256, 0, stream>>>((unsigned*)vT);
    k_qkv_mfma<<<391, 256, 0, stream>>>(z, Wcb, bext, vbuf, qp, kpb, stab);
    k_deg<<<3125, 256, 0, stream>>>(ei, din, dout_);
    k_scan_part<<<196, 256, 0, stream>>>(din, bsum);
    k_scan_top<<<1, 64, 0, stream>>>(bsum, boff);
    k_scan_fin<<<196, 256, 0, stream>>>(din, boff, offsets, cursor, dout_, rsd);
    k_kp<<<512, 256, 0, stream>>>(kpb, stab, kp_sum, kp_bf);      // raw kpb dead after this
    k_scatter<<<3125, 256, 0, stream>>>(ei, cursor, csr_pack);
    k_vt<<<dim3(782, 4), 256, 0, stream>>>(vbuf, vT);
    k_kvs<<<dim3(KVSNB, 4), 256, 0, stream>>>(kp_bf, g, vT, kvs, ktg);
    k_kvsbf<<<320, 256, 0, stream>>>(kvs, kvs_bfT);
    k_znext_mfma<<<dim3(782, 4), 256, 0, stream>>>(qp, kvs_bfT, ktg, kp_sum, znext, qpn_bf);
    k_vr<<<12500, 256, 0, stream>>>(vbuf, rsd, vr);                 // vr aliases qp (dead now)
    k_convedge<<<12500, 256, 0, stream>>>(offsets, csr_pack, din, vr, kp_bf,
                                          qpn_bf, brb, znext, A_scratch);
    k_out<<<196, 256, 0, stream>>>(znext, WoT, Wob, out);
    hipMemcpyAsync(A, A_scratch, (size_t)EE*4*sizeof(float), hipMemcpyDeviceToDevice, stream);
}

// Round 24
// 632.502 us; speedup vs baseline: 1.0624x; 1.0130x over previous
//
#include <hip/hip_runtime.h>

#define NN 50000
#define EE 800000
#define IND 128
#define NCOL 1024
#define KM 320            // K * Mpad = 10*32
#define M30 30
#define RATIO 0.1825741858f   // 30^-0.5
#define EPSF 1e-6f
#define QKSCALE 0.7071067812f // (1/sqrt(0.25)) * 64^-0.25
#define VTS 50176             // vT row stride (196*256)
#define KVSNB 196             // k_kvs node-chunk blocks (256 nodes each)
#define AST 136               // a-tile LDS row stride in bf16 (2-way-free banks)

typedef __attribute__((ext_vector_type(8))) short bf16x8;
typedef __attribute__((ext_vector_type(4))) float f32x4;

__device__ __forceinline__ unsigned f2s(float f) {
    unsigned u = __float_as_uint(f);
    return (u & 0x80000000u) ? ~u : (u | 0x80000000u);
}
__device__ __forceinline__ float s2f(unsigned s) {
    return __uint_as_float((s & 0x80000000u) ? (s & 0x7fffffffu) : ~s);
}
__device__ __forceinline__ unsigned short f2bf(float f) {   // RTNE fp32->bf16
    unsigned u = __float_as_uint(f);
    unsigned r = u + 0x7fffu + ((u >> 16) & 1u);
    return (unsigned short)(r >> 16);
}
__device__ __forceinline__ float bf2f(unsigned short h) {
    return __uint_as_float(((unsigned)h) << 16);
}

// ---------- prep: Wt[IND][NCOL] (cols: 0-255 s*Wq^T, 256-511 s*Wk^T, 512-767 Wv^T,
// 768-895 Pq[h,m], 896-1023 Pk[h,m]), bias_ext[NCOL], WoT[256][64]
__global__ void k_prep(const float* __restrict__ Wq, const float* __restrict__ Wqb,
                       const float* __restrict__ Wk, const float* __restrict__ Wkb,
                       const float* __restrict__ Wv, const float* __restrict__ Wvb,
                       const float* __restrict__ Wo, const float* __restrict__ proj,
                       float* __restrict__ Wt, float* __restrict__ bext, float* __restrict__ WoT) {
    int i = blockIdx.x;   // 0..127
    int t = threadIdx.x;  // 0..255
    Wt[i*NCOL + t]       = QKSCALE * Wq[t*IND + i];
    Wt[i*NCOL + 256 + t] = QKSCALE * Wk[t*IND + i];
    Wt[i*NCOL + 512 + t] = Wv[t*IND + i];
    {
        const float* W = (t < 128) ? Wq : Wk;
        int c = (t < 128) ? t : (t - 128);
        int h = c >> 5, m = c & 31;
        float val = 0.f;
        if (m < M30) {
            for (int d = 0; d < 64; ++d)
                val += QKSCALE * W[(h*64+d)*IND + i] * proj[m*64 + d];
        }
        Wt[i*NCOL + 768 + t] = val;
    }
    if (t < 128) {
        int f = i*2 + (t >> 6);
        int o = t & 63;
        WoT[f*64 + o] = Wo[o*256 + f];
    }
    if (i == 0) {
        bext[t]       = QKSCALE * Wqb[t];
        bext[256 + t] = QKSCALE * Wkb[t];
        bext[512 + t] = Wvb[t];
        const float* Bb = (t < 128) ? Wqb : Wkb;
        int c = (t < 128) ? t : (t - 128);
        int h = c >> 5, m = c & 31;
        float val = 0.f;
        if (m < M30) {
            for (int d = 0; d < 64; ++d)
                val += QKSCALE * Bb[h*64+d] * proj[m*64 + d];
        }
        bext[768 + t] = val;
    }
}

// ---------- Wcb: bf16 hi/lo split of Wt, layout [col][k] (MFMA B operand)
__global__ void k_prep2(const float* __restrict__ Wt, unsigned short* __restrict__ Wcb) {
    int idx = blockIdx.x*256 + threadIdx.x;   // 512 blocks -> 131072
    int col = idx >> 7, k = idx & 127;
    float f = Wt[k*NCOL + col];
    unsigned short hi = f2bf(f);
    unsigned short lo = f2bf(f - bf2f(hi));
    Wcb[col*128 + k] = hi;
    Wcb[131072 + col*128 + k] = lo;
}

// ---------- zero vT tail cols [50000,50176) (vT aliases znext; replay determinism)
__global__ void k_ztail(unsigned* __restrict__ vT32) {
    int idx = blockIdx.x*256 + threadIdx.x;  // 88 blocks * 256 = 22528 = 256*88
    int row = idx / 88, c = idx - row*88;
    vT32[(size_t)row * (VTS/2) + (50000/2) + c] = 0u;
}

// ---------- fused QKV+dash GEMM via bf16x2 MFMA (A single-rounded, B hi+lo).
// 128 nodes/block, nt split into outer 2-half loop: live acc[8][2]=64 VGPR
// (round-23 fix: kills the spill that cost ~35us at acc[8][4]).
__global__ __launch_bounds__(256) void k_qkv_mfma(const float* __restrict__ z,
                      const unsigned short* __restrict__ Wcb, const float* __restrict__ bext,
                      float* __restrict__ vbuf, float* __restrict__ qp, float* __restrict__ kpb,
                      unsigned* __restrict__ stab) {
    __shared__ __align__(16) unsigned short a_hi[128*AST];
    __shared__ float diag_l[2][4][128];   // [q/k][head][node]
    int t = threadIdx.x;
    int n0 = blockIdx.x * 128;
    int w = t >> 6, lane = t & 63;
    #pragma unroll
    for (int half = 0; half < 2; ++half) {
        int node = (t >> 2) + half*64;
        int ks = (t & 3) * 32;
        bool ok = (n0 + node) < NN;
        const float* zr = z + (size_t)(n0 + node)*IND + ks;
        unsigned hbuf[16];
        #pragma unroll
        for (int c = 0; c < 8; ++c) {
            float4 v = ok ? *(const float4*)(zr + c*4) : make_float4(0.f,0.f,0.f,0.f);
            hbuf[c*2]   = (unsigned)f2bf(v.x) | ((unsigned)f2bf(v.y) << 16);
            hbuf[c*2+1] = (unsigned)f2bf(v.z) | ((unsigned)f2bf(v.w) << 16);
        }
        uint4* hp = (uint4*)(&a_hi[node*AST + ks]);
        #pragma unroll
        for (int c = 0; c < 4; ++c)
            hp[c] = make_uint4(hbuf[c*4], hbuf[c*4+1], hbuf[c*4+2], hbuf[c*4+3]);
    }
    __syncthreads();
    int arow = lane & 15;
    int ao = (lane >> 4) * 8;
    for (int c = 0; c < 4; ++c) {
        int colbase = c*256 + w*64;
        float dsum[8][4];                 // diag partials (live only for c<2)
        if (c < 2) {
            #pragma unroll
            for (int mt = 0; mt < 8; ++mt)
                #pragma unroll
                for (int r = 0; r < 4; ++r) dsum[mt][r] = 0.f;
        }
        #pragma unroll
        for (int half = 0; half < 2; ++half) {
            f32x4 acc[8][2];
            #pragma unroll
            for (int mt = 0; mt < 8; ++mt)
                #pragma unroll
                for (int ntl = 0; ntl < 2; ++ntl)
                    acc[mt][ntl] = (f32x4){0.f,0.f,0.f,0.f};
            #pragma unroll
            for (int ks = 0; ks < 4; ++ks) {
                int ko = ks*32 + ao;
                bf16x8 Ah[8];
                #pragma unroll
                for (int mt = 0; mt < 8; ++mt)
                    Ah[mt] = *(const bf16x8*)(&a_hi[(mt*16 + arow)*AST + ko]);
                #pragma unroll
                for (int ntl = 0; ntl < 2; ++ntl) {
                    int nt = half*2 + ntl;
                    const unsigned short* bp = Wcb + (size_t)(colbase + nt*16 + arow)*128 + ko;
                    bf16x8 Bh = *(const bf16x8*)bp;
                    bf16x8 Bl = *(const bf16x8*)(bp + 131072);
                    #pragma unroll
                    for (int mt = 0; mt < 8; ++mt) {
                        acc[mt][ntl] = __builtin_amdgcn_mfma_f32_16x16x32_bf16(Ah[mt], Bh, acc[mt][ntl], 0, 0, 0);
                        acc[mt][ntl] = __builtin_amdgcn_mfma_f32_16x16x32_bf16(Ah[mt], Bl, acc[mt][ntl], 0, 0, 0);
                    }
                }
            }
            // bias (per col)
            float bv[2];
            #pragma unroll
            for (int ntl = 0; ntl < 2; ++ntl)
                bv[ntl] = bext[colbase + (half*2 + ntl)*16 + arow];
            #pragma unroll
            for (int mt = 0; mt < 8; ++mt)
                #pragma unroll
                for (int ntl = 0; ntl < 2; ++ntl)
                    #pragma unroll
                    for (int r = 0; r < 4; ++r)
                        acc[mt][ntl][r] += bv[ntl];
            // D layout: row = 16mt + (lane>>4)*4 + r, col = 16*(half*2+ntl) + (lane&15)
            if (c < 2) {
                #pragma unroll
                for (int mt = 0; mt < 8; ++mt)
                    #pragma unroll
                    for (int r = 0; r < 4; ++r)
                        dsum[mt][r] += acc[mt][0][r]*acc[mt][0][r] + acc[mt][1][r]*acc[mt][1][r];
            } else if (c == 2) {
                #pragma unroll
                for (int mt = 0; mt < 8; ++mt)
                    #pragma unroll
                    for (int r = 0; r < 4; ++r) {
                        int node = n0 + mt*16 + (lane>>4)*4 + r;
                        if (node < NN) {
                            #pragma unroll
                            for (int ntl = 0; ntl < 2; ++ntl)
                                vbuf[(size_t)node*256 + w*64 + (half*2+ntl)*16 + arow] = acc[mt][ntl][r];
                        }
                    }
            } else {
                int hh = (w & 1) * 2;
                int p = half;            // nt pair {2p, 2p+1} == this half
                int h = hh + p;
                if (w < 2) {
                    // q-dash -> qp
                    #pragma unroll
                    for (int mt = 0; mt < 8; ++mt) {
                        #pragma unroll
                        for (int r = 0; r < 4; ++r) {
                            int row = mt*16 + (lane>>4)*4 + r;
                            float dg = diag_l[0][h][row];
                            float mx = fmaxf(acc[mt][0][r],
                                             (arow < 14) ? acc[mt][1][r] : -3.0e38f);
                            mx = fmaxf(mx, __shfl_xor(mx, 1)); mx = fmaxf(mx, __shfl_xor(mx, 2));
                            mx = fmaxf(mx, __shfl_xor(mx, 4)); mx = fmaxf(mx, __shfl_xor(mx, 8));
                            int node = n0 + row;
                            if (node < NN) {
                                #pragma unroll
                                for (int q2 = 0; q2 < 2; ++q2) {
                                    int m = q2*16 + arow;
                                    float val = 0.f;
                                    if (m < M30)
                                        val = RATIO * (__expf(acc[mt][q2][r] - dg - mx) + EPSF);
                                    qp[(size_t)node*128 + h*32 + m] = val;
                                }
                            }
                        }
                    }
                } else {
                    // k-dash -> kpb raw + stab
                    float smax = -3.0e38f;
                    #pragma unroll
                    for (int mt = 0; mt < 8; ++mt) {
                        #pragma unroll
                        for (int r = 0; r < 4; ++r) {
                            int row = mt*16 + (lane>>4)*4 + r;
                            float dg = diag_l[1][h][row];
                            int node = n0 + row;
                            if (node < NN) {
                                #pragma unroll
                                for (int q2 = 0; q2 < 2; ++q2) {
                                    int m = q2*16 + arow;
                                    float d = acc[mt][q2][r];
                                    bool valid = (m < M30);
                                    kpb[(size_t)node*128 + h*32 + m] = valid ? (d - dg) : 0.f;
                                    if (valid) smax = fmaxf(smax, d);
                                }
                            }
                        }
                    }
                    smax = fmaxf(smax, __shfl_xor(smax, 1));  smax = fmaxf(smax, __shfl_xor(smax, 2));
                    smax = fmaxf(smax, __shfl_xor(smax, 4));  smax = fmaxf(smax, __shfl_xor(smax, 8));
                    smax = fmaxf(smax, __shfl_xor(smax, 16)); smax = fmaxf(smax, __shfl_xor(smax, 32));
                    if (lane == 0) atomicMax(&stab[h], f2s(smax));
                }
            }
        }
        if (c < 2) {
            #pragma unroll
            for (int mt = 0; mt < 8; ++mt) {
                #pragma unroll
                for (int r = 0; r < 4; ++r) {
                    float s = dsum[mt][r];
                    s += __shfl_xor(s, 1); s += __shfl_xor(s, 2);
                    s += __shfl_xor(s, 4); s += __shfl_xor(s, 8);
                    if (arow == 0) diag_l[c][w][mt*16 + (lane>>4)*4 + r] = 0.5f*s;
                }
            }
        }
        __syncthreads();
    }
}

// ---------- vT[c][n] = bf16(vbuf[n][c]) tiled transpose (64x64 tiles via LDS)
__global__ __launch_bounds__(256) void k_vt(const float* __restrict__ vbuf,
                      unsigned short* __restrict__ vT) {
    __shared__ unsigned short tile[64][72];
    int t = threadIdx.x;
    int n0 = blockIdx.x * 64;
    int c0 = blockIdx.y * 64;
    {
        int node = t >> 2, cs = (t & 3) * 16;
        bool ok = (n0 + node) < NN;
        const float* vr = vbuf + (size_t)(n0 + node)*256 + c0 + cs;
        #pragma unroll
        for (int cc = 0; cc < 4; ++cc) {
            float4 v = ok ? *(const float4*)(vr + cc*4) : make_float4(0.f,0.f,0.f,0.f);
            unsigned u0 = (unsigned)f2bf(v.x) | ((unsigned)f2bf(v.y) << 16);
            unsigned u1 = (unsigned)f2bf(v.z) | ((unsigned)f2bf(v.w) << 16);
            *(unsigned*)(&tile[node][cs + cc*4])     = u0;
            *(unsigned*)(&tile[node][cs + cc*4 + 2]) = u1;
        }
    }
    __syncthreads();
    {
        int d = t >> 2, ns = (t & 3) * 16;
        unsigned ob[8];
        #pragma unroll
        for (int i = 0; i < 8; ++i) {
            unsigned short a = tile[ns + i*2][d];
            unsigned short b = tile[ns + i*2 + 1][d];
            ob[i] = (unsigned)a | ((unsigned)b << 16);
        }
        unsigned short* op = vT + (size_t)(c0 + d)*VTS + n0 + ns;
        *(uint4*)(op)     = make_uint4(ob[0], ob[1], ob[2], ob[3]);
        *(uint4*)(op + 8) = make_uint4(ob[4], ob[5], ob[6], ob[7]);
    }
}

__global__ void k_deg(const int* __restrict__ ei, int* __restrict__ din, int* __restrict__ dout) {
    int e = blockIdx.x*256 + threadIdx.x;
    if (e < EE) {
        atomicAdd(&dout[ei[e]], 1);
        atomicAdd(&din[ei[EE + e]], 1);
    }
}

// ---------- prefix sum over din (3-kernel scan) ----------
__global__ void k_scan_part(const int* __restrict__ din, int* __restrict__ bsum) {
    __shared__ int red[256];
    int t = threadIdx.x;
    int i = blockIdx.x*256 + t;
    red[t] = (i < NN) ? din[i] : 0;
    __syncthreads();
    for (int off = 128; off >= 1; off >>= 1) {
        if (t < off) red[t] += red[t+off];
        __syncthreads();
    }
    if (t == 0) bsum[blockIdx.x] = red[0];
}
__global__ void k_scan_top(const int* __restrict__ bsum, int* __restrict__ boff) {
    if (threadIdx.x == 0) {
        int acc = 0;
        for (int b = 0; b < 196; ++b) { boff[b] = acc; acc += bsum[b]; }
    }
}
// scan finish + rsd = rsqrt(dout) (k_rs folded in)
__global__ void k_scan_fin(const int* __restrict__ din, const int* __restrict__ boff,
                           int* __restrict__ offsets, int* __restrict__ cursor,
                           const int* __restrict__ dout_, float* __restrict__ rsd) {
    __shared__ int s[256];
    int t = threadIdx.x;
    int i = blockIdx.x*256 + t;
    if (i < NN) {
        int d = dout_[i];
        rsd[i] = d > 0 ? rsqrtf((float)d) : 0.f;
    }
    int v = (i < NN) ? din[i] : 0;
    s[t] = v;
    __syncthreads();
    for (int off = 1; off < 256; off <<= 1) {
        int add = (t >= off) ? s[t-off] : 0;
        __syncthreads();
        s[t] += add;
        __syncthreads();
    }
    int excl = s[t] - v + boff[blockIdx.x];
    if (i < NN) { offsets[i] = excl; cursor[i] = excl; }
    if (i == NN-1) offsets[NN] = excl + v;
}

// scatter (row, eid) packed as int2 into CSR-by-col order
__global__ void k_scatter(const int* __restrict__ ei, int* __restrict__ cursor,
                          int2* __restrict__ csr_pack) {
    int e = blockIdx.x*256 + threadIdx.x;
    if (e < EE) {
        int col = ei[EE + e];
        int pos = atomicAdd(&cursor[col], 1);
        csr_pack[pos] = make_int2(ei[e], e);
    }
}

// ---------- finish kp = ratio*(exp(dash-diag-stab)+eps) -> kp_bf (bf16); kp_sum[h][m]
__global__ void k_kp(const float* __restrict__ kpb, const unsigned* __restrict__ stab,
                     float* __restrict__ kp_sum, unsigned short* __restrict__ kp_bf) {
    __shared__ float red[256];
    int t = threadIdx.x;
    int hm = t & 127;
    int h = hm >> 5, m = hm & 31;
    float st = s2f(stab[h]);
    float ksum = 0.f;
    const int total = NN*128;
    for (int idx = blockIdx.x*256 + t; idx < total; idx += gridDim.x*256) {
        float val = kpb[idx];
        float kpv = 0.f;
        if (m < M30) kpv = RATIO * (__expf(val - st) + EPSF);
        kp_bf[idx] = f2bf(kpv);
        ksum += kpv;
    }
    red[t] = ksum;
    __syncthreads();
    if (t < 128) atomicAdd(&kp_sum[hm], red[t] + red[t+128]);
}

// ---------- kvs[h][km][d] = sum_n w[n,km]*v[n,d] via MFMA (16x16x32 bf16).
__global__ __launch_bounds__(256) void k_kvs(const unsigned short* __restrict__ kp_bf,
                      const float* __restrict__ g, const unsigned short* __restrict__ vT,
                      float* __restrict__ kvs, float* __restrict__ ktg) {
    __shared__ __align__(16) unsigned short w_l[320*40]; // row stride 40 bf16 (80B)
    __shared__ __align__(16) unsigned short v_l[64*40];
    __shared__ __align__(16) float eg_l[10][36];
    __shared__ float kp_lf[32][33];                      // 32 nodes x 32 m (pad 33)
    int t = threadIdx.x;
    int h = blockIdx.y;
    int n0b = blockIdx.x * 256;
    int lane = t & 63;
    int wb = (t >> 6) * 80;            // wave's km base
    int arow = lane & 15;
    int acol = (lane >> 4) * 8;        // bf16 col offset of the 8-elem fragment
    f32x4 acc[5][4];
    #pragma unroll
    for (int kt = 0; kt < 5; ++kt)
        #pragma unroll
        for (int dt = 0; dt < 4; ++dt)
            acc[kt][dt] = (f32x4){0.f, 0.f, 0.f, 0.f};
    float wsum0 = 0.f, wsum1 = 0.f;
    int k0 = t >> 5, m0 = t & 31;      // row t = k0*32 + m0
    int k1 = 8 + (t >> 5), m1 = t & 31; // row t+256 (t<64)

    for (int st = 0; st < 8; ++st) {
        int n0 = n0b + st * 32;
        __syncthreads();               // prev tile consumed by MFMA
        #pragma unroll
        for (int i = 0; i < 2; ++i) {
            int flat = t + i*256;
            if (flat < 320) {
                int kk = flat % 10, n = flat / 10;
                float e = 0.f;
                if (n0 + n < NN) e = __expf(g[(size_t)(n0+n)*40 + h*10 + kk]);
                eg_l[kk][n] = e;
            }
        }
        {
            int d = t >> 2, seg = t & 3;
            uint4 vv = *(const uint4*)(vT + (size_t)(h*64 + d)*VTS + n0 + seg*8);
            *(uint4*)(&v_l[d*40 + seg*8]) = vv;
        }
        if (t < 128) {
            int n = t >> 2, seg = t & 3;
            int gn = n0 + n;
            if (gn < NN) {
                uint4 kv = *(const uint4*)(kp_bf + (size_t)gn*128 + h*32 + seg*8);
                unsigned uu[4] = {kv.x, kv.y, kv.z, kv.w};
                #pragma unroll
                for (int j = 0; j < 4; ++j) {
                    kp_lf[n][seg*8 + j*2]     = __uint_as_float(uu[j] << 16);
                    kp_lf[n][seg*8 + j*2 + 1] = __uint_as_float(uu[j] & 0xFFFF0000u);
                }
            } else {
                #pragma unroll
                for (int j = 0; j < 8; ++j) kp_lf[n][seg*8 + j] = 0.f;
            }
        }
        __syncthreads();
        {
            // row t
            {
                unsigned dw[16];
                float s = 0.f;
                #pragma unroll
                for (int c = 0; c < 16; ++c) {
                    float kpa = kp_lf[c*2][m0];
                    float kpc = kp_lf[c*2+1][m0];
                    unsigned ua = __float_as_uint(kpa * eg_l[k0][c*2]);
                    unsigned ub = __float_as_uint(kpc * eg_l[k0][c*2+1]);
                    s += __uint_as_float(ua & 0xFFFF0000u) + __uint_as_float(ub & 0xFFFF0000u);
                    dw[c] = (ua >> 16) | (ub & 0xFFFF0000u);
                }
                wsum0 += s;
                uint4* wp = (uint4*)(&w_l[t*40]);
                wp[0] = make_uint4(dw[0], dw[1], dw[2],  dw[3]);
                wp[1] = make_uint4(dw[4], dw[5], dw[6],  dw[7]);
                wp[2] = make_uint4(dw[8], dw[9], dw[10], dw[11]);
                wp[3] = make_uint4(dw[12],dw[13],dw[14], dw[15]);
            }
            if (t < 64) {
                unsigned dw[16];
                float s = 0.f;
                #pragma unroll
                for (int c = 0; c < 16; ++c) {
                    float kpa = kp_lf[c*2][m1];
                    float kpc = kp_lf[c*2+1][m1];
                    unsigned ua = __float_as_uint(kpa * eg_l[k1][c*2]);
                    unsigned ub = __float_as_uint(kpc * eg_l[k1][c*2+1]);
                    s += __uint_as_float(ua & 0xFFFF0000u) + __uint_as_float(ub & 0xFFFF0000u);
                    dw[c] = (ua >> 16) | (ub & 0xFFFF0000u);
                }
                wsum1 += s;
                uint4* wp = (uint4*)(&w_l[(t + 256)*40]);
                wp[0] = make_uint4(dw[0], dw[1], dw[2],  dw[3]);
                wp[1] = make_uint4(dw[4], dw[5], dw[6],  dw[7]);
                wp[2] = make_uint4(dw[8], dw[9], dw[10], dw[11]);
                wp[3] = make_uint4(dw[12],dw[13],dw[14], dw[15]);
            }
        }
        __syncthreads();
        bf16x8 Bf[4];
        #pragma unroll
        for (int dt = 0; dt < 4; ++dt)
            Bf[dt] = *(const bf16x8*)(&v_l[(dt*16 + arow)*40 + acol]);
        #pragma unroll
        for (int kt = 0; kt < 5; ++kt) {
            bf16x8 Af = *(const bf16x8*)(&w_l[(wb + kt*16 + arow)*40 + acol]);
            #pragma unroll
            for (int dt = 0; dt < 4; ++dt)
                acc[kt][dt] = __builtin_amdgcn_mfma_f32_16x16x32_bf16(Af, Bf[dt], acc[kt][dt], 0, 0, 0);
        }
    }
    {
        int orow = (lane >> 4) * 4;
        int ocol = lane & 15;
        float* kb = kvs + h*KM*64;
        #pragma unroll
        for (int kt = 0; kt < 5; ++kt)
            #pragma unroll
            for (int dt = 0; dt < 4; ++dt)
                #pragma unroll
                for (int r = 0; r < 4; ++r)
                    atomicAdd(&kb[(wb + kt*16 + orow + r)*64 + dt*16 + ocol], acc[kt][dt][r]);
        atomicAdd(&ktg[h*KM + t], wsum0);
        if (t < 64) atomicAdd(&ktg[h*KM + 256 + t], wsum1);
    }
}

// ---------- kvs_bfT[h][d][km] = bf16(kvs[h][km][d])  (B operand for k_znext_mfma)
__global__ void k_kvsbf(const float* __restrict__ kvs, unsigned short* __restrict__ kvs_bfT) {
    int idx = blockIdx.x*256 + threadIdx.x;   // 320 blocks -> 81920 exact
    int h = idx / 20480;
    int rem = idx - h*20480;
    int d = rem / 320;
    int km = rem - d*320;
    kvs_bfT[idx] = f2bf(kvs[(size_t)h*20480 + km*64 + d]);
}

// ---------- znext via MFMA: A[n][k*32+m] = qpn[n][m]*rd[n][k] (bf16, LDS),
// B = kvs_bfT[h][d][km]. D[n][d] = znext. Also emits qpn_bf.
__global__ __launch_bounds__(256) void k_znext_mfma(const float* __restrict__ qp,
                        const unsigned short* __restrict__ kvs_bfT,
                        const float* __restrict__ ktg, const float* __restrict__ kp_sum,
                        float* __restrict__ znext, unsigned short* __restrict__ qpn_bf) {
    __shared__ __align__(16) unsigned short A_l[64*328];
    __shared__ float ktg_l[320];
    __shared__ float ksum_l[32];
    int t = threadIdx.x;
    int h = blockIdx.y;
    int n0 = blockIdx.x * 64;
    ktg_l[t] = ktg[h*KM + t];
    if (t < 64) ktg_l[256 + t] = ktg[h*KM + 256 + t];
    if (t < 32) ksum_l[t] = kp_sum[h*32 + t];
    __syncthreads();
    // ---- phase 1: thread = node*4 + p; p owns m in [p*8, p*8+8)
    {
        int node = t >> 2, p = t & 3;
        int n = n0 + node;
        bool ok = (n < NN);
        float q8[8];
        if (ok) {
            const float* qb = qp + (size_t)n*128 + h*32 + p*8;
            float4 a = *(const float4*)(qb);
            float4 b = *(const float4*)(qb + 4);
            q8[0]=a.x; q8[1]=a.y; q8[2]=a.z; q8[3]=a.w;
            q8[4]=b.x; q8[5]=b.y; q8[6]=b.z; q8[7]=b.w;
        } else {
            #pragma unroll
            for (int j = 0; j < 8; ++j) q8[j] = 0.f;
        }
        float part = 0.f;
        #pragma unroll
        for (int j = 0; j < 8; ++j) part = fmaf(q8[j], ksum_l[p*8 + j], part);
        part += __shfl_xor(part, 1); part += __shfl_xor(part, 2);
        float rn = ok ? (1.f / part) : 0.f;
        #pragma unroll
        for (int j = 0; j < 8; ++j) q8[j] *= rn;
        if (ok) {
            unsigned ob[4];
            #pragma unroll
            for (int c = 0; c < 4; ++c)
                ob[c] = (unsigned)f2bf(q8[c*2]) | ((unsigned)f2bf(q8[c*2+1]) << 16);
            *(uint4*)(qpn_bf + (size_t)n*128 + h*32 + p*8) = make_uint4(ob[0], ob[1], ob[2], ob[3]);
        }
        #pragma unroll
        for (int k = 0; k < 10; ++k) {
            float dp = 0.f;
            #pragma unroll
            for (int j = 0; j < 8; ++j) dp = fmaf(q8[j], ktg_l[k*32 + p*8 + j], dp);
            dp += __shfl_xor(dp, 1); dp += __shfl_xor(dp, 2);
            float rd = ok ? (1.f / (dp * 10.f)) : 0.f;
            unsigned ob[4];
            #pragma unroll
            for (int c = 0; c < 4; ++c)
                ob[c] = (unsigned)f2bf(q8[c*2]*rd) | ((unsigned)f2bf(q8[c*2+1]*rd) << 16);
            *(uint4*)(&A_l[node*328 + k*32 + p*8]) = make_uint4(ob[0], ob[1], ob[2], ob[3]);
        }
    }
    __syncthreads();
    // ---- phase 2: wave w = 16-d N-tile; 4 M-tiles; 10 K-steps
    {
        int lane = t & 63, w = t >> 6;
        int arow = lane & 15;
        int ao = (lane >> 4) * 8;
        f32x4 acc[4];
        #pragma unroll
        for (int mt = 0; mt < 4; ++mt) acc[mt] = (f32x4){0.f,0.f,0.f,0.f};
        const unsigned short* Bb = kvs_bfT + (size_t)h*20480 + (w*16 + arow)*320;
        #pragma unroll
        for (int ks = 0; ks < 10; ++ks) {
            bf16x8 Bf = *(const bf16x8*)(Bb + ks*32 + ao);
            #pragma unroll
            for (int mt = 0; mt < 4; ++mt) {
                bf16x8 Af = *(const bf16x8*)(&A_l[(mt*16 + arow)*328 + ks*32 + ao]);
                acc[mt] = __builtin_amdgcn_mfma_f32_16x16x32_bf16(Af, Bf, acc[mt], 0, 0, 0);
            }
        }
        #pragma unroll
        for (int mt = 0; mt < 4; ++mt)
            #pragma unroll
            for (int r = 0; r < 4; ++r) {
                int n = n0 + mt*16 + (lane>>4)*4 + r;
                if (n < NN)
                    znext[(size_t)n*256 + h*64 + w*16 + arow] = acc[mt][r];
            }
    }
}

// ---------- FUSED conv + edge over CSR, 4-edge unrolled (8 gathers in flight;
// round-15's 2-edge unroll gave 187->123us by the same MLP mechanism).
__global__ __launch_bounds__(256) void k_convedge(const int* __restrict__ offsets,
                        const int2* __restrict__ csr_pack,
                        const int* __restrict__ din, const unsigned short* __restrict__ vr,
                        const unsigned short* __restrict__ kp_bf,
                        const unsigned short* __restrict__ qpn_bf,
                        const float* __restrict__ brb, float* __restrict__ znext,
                        float* __restrict__ A) {
    __shared__ unsigned short qpn_l[4][128];
    int t = threadIdx.x;
    int w = t >> 6, lane = t & 63;
    int col = blockIdx.x*4 + w;          // grid exact: col < NN always
    if (lane < 8) {
        uint4 q4 = *(const uint4*)(qpn_bf + (size_t)col*128 + lane*8);
        *(uint4*)(&qpn_l[w][lane*8]) = q4;
    }
    __syncthreads();
    int s0 = offsets[col], s1 = offsets[col+1];
    int hq = (lane & 31) >> 3;
    float qv0, qv1, qv2, qv3;
    {
        ushort4 qq = *(const ushort4*)(&qpn_l[w][hq*32 + (lane & 7)*4]);
        qv0 = bf2f(qq.x); qv1 = bf2f(qq.y); qv2 = bf2f(qq.z); qv3 = bf2f(qq.w);
    }
    bool dowrite = (lane < 32) && ((lane & 7) == 0);
    float a0 = 0.f, a1 = 0.f, a2 = 0.f, a3 = 0.f;
    int j = s0;
    for (; j + 4 <= s1; j += 4) {
        int2 p0 = csr_pack[j];
        int2 p1 = csr_pack[j+1];
        int2 p2 = csr_pack[j+2];
        int2 p3 = csr_pack[j+3];
        // issue all 8 gathers before any reduction
        ushort4 u0 = *(const ushort4*)(vr + (size_t)p0.x*256 + lane*4);
        ushort4 u1 = *(const ushort4*)(vr + (size_t)p1.x*256 + lane*4);
        ushort4 u2 = *(const ushort4*)(vr + (size_t)p2.x*256 + lane*4);
        ushort4 u3 = *(const ushort4*)(vr + (size_t)p3.x*256 + lane*4);
        ushort4 k0 = *(const ushort4*)(kp_bf + (size_t)p0.x*128 + (lane & 31)*4);
        ushort4 k1 = *(const ushort4*)(kp_bf + (size_t)p1.x*128 + (lane & 31)*4);
        ushort4 k2 = *(const ushort4*)(kp_bf + (size_t)p2.x*128 + (lane & 31)*4);
        ushort4 k3 = *(const ushort4*)(kp_bf + (size_t)p3.x*128 + (lane & 31)*4);
        a0 += bf2f(u0.x) + bf2f(u1.x) + bf2f(u2.x) + bf2f(u3.x);
        a1 += bf2f(u0.y) + bf2f(u1.y) + bf2f(u2.y) + bf2f(u3.y);
        a2 += bf2f(u0.z) + bf2f(u1.z) + bf2f(u2.z) + bf2f(u3.z);
        a3 += bf2f(u0.w) + bf2f(u1.w) + bf2f(u2.w) + bf2f(u3.w);
        float d0 = qv0*bf2f(k0.x) + qv1*bf2f(k0.y) + qv2*bf2f(k0.z) + qv3*bf2f(k0.w);
        float d1 = qv0*bf2f(k1.x) + qv1*bf2f(k1.y) + qv2*bf2f(k1.z) + qv3*bf2f(k1.w);
        float d2 = qv0*bf2f(k2.x) + qv1*bf2f(k2.y) + qv2*bf2f(k2.z) + qv3*bf2f(k2.w);
        float d3 = qv0*bf2f(k3.x) + qv1*bf2f(k3.y) + qv2*bf2f(k3.z) + qv3*bf2f(k3.w);
        d0 += __shfl_xor(d0, 1); d1 += __shfl_xor(d1, 1); d2 += __shfl_xor(d2, 1); d3 += __shfl_xor(d3, 1);
        d0 += __shfl_xor(d0, 2); d1 += __shfl_xor(d1, 2); d2 += __shfl_xor(d2, 2); d3 += __shfl_xor(d3, 2);
        d0 += __shfl_xor(d0, 4); d1 += __shfl_xor(d1, 4); d2 += __shfl_xor(d2, 4); d3 += __shfl_xor(d3, 4);
        if (dowrite) {
            A[(size_t)p0.y*4 + hq] = d0;
            A[(size_t)p1.y*4 + hq] = d1;
            A[(size_t)p2.y*4 + hq] = d2;
            A[(size_t)p3.y*4 + hq] = d3;
        }
    }
    for (; j < s1; ++j) {
        int2 p0 = csr_pack[j];
        ushort4 u0 = *(const ushort4*)(vr + (size_t)p0.x*256 + lane*4);
        ushort4 k0 = *(const ushort4*)(kp_bf + (size_t)p0.x*128 + (lane & 31)*4);
        a0 += bf2f(u0.x); a1 += bf2f(u0.y); a2 += bf2f(u0.z); a3 += bf2f(u0.w);
        float d0 = qv0*bf2f(k0.x) + qv1*bf2f(k0.y) + qv2*bf2f(k0.z) + qv3*bf2f(k0.w);
        d0 += __shfl_xor(d0, 1); d0 += __shfl_xor(d0, 2); d0 += __shfl_xor(d0, 4);
        if (dowrite) A[(size_t)p0.y*4 + hq] = d0;
    }
    if (s0 == s1) return;
    int h = lane >> 4;
    float sig = 1.f / (1.f + __expf(-brb[h]));
    float sc = sig * rsqrtf((float)din[col]);
    float* zp = znext + (size_t)col*256 + lane*4;
    float4 zv = *(float4*)zp;
    zv.x += sc*a0; zv.y += sc*a1; zv.z += sc*a2; zv.w += sc*a3;
    *(float4*)zp = zv;
}

// ---------- vr[row] = rsd[row] * v[row], bf16-compressed
__global__ __launch_bounds__(256) void k_vr(const float* __restrict__ vbuf,
                      const float* __restrict__ rsd, unsigned short* __restrict__ vr) {
    int t = threadIdx.x;
    int row = blockIdx.x*4 + (t >> 6);
    int lane = t & 63;
    float rs = rsd[row];
    float4 v4 = *(const float4*)(vbuf + (size_t)row*256 + lane*4);
    ushort4 o;
    o.x = f2bf(rs * v4.x);
    o.y = f2bf(rs * v4.y);
    o.z = f2bf(rs * v4.z);
    o.w = f2bf(rs * v4.w);
    *(ushort4*)(vr + (size_t)row*256 + lane*4) = o;
}

// ---------- out[n][o] = sum_f znext[n][f] * Wo[o][f] + Wob[o]
__global__ __launch_bounds__(256) void k_out(const float* __restrict__ znext, const float* __restrict__ WoT,
                      const float* __restrict__ Wob, float* __restrict__ out) {
    int n = blockIdx.x*256 + threadIdx.x;
    if (n >= NN) return;
    float acc[64];
    #pragma unroll
    for (int o = 0; o < 64; ++o) acc[o] = Wob[o];
    const float* zr = znext + (size_t)n*256;
    for (int fc = 0; fc < 64; ++fc) {
        float4 z4 = *(const float4*)(zr + fc*4);
        float zz[4] = {z4.x, z4.y, z4.z, z4.w};
        #pragma unroll
        for (int j = 0; j < 4; ++j) {
            const float* wr = WoT + (fc*4+j)*64;
            #pragma unroll
            for (int o = 0; o < 64; ++o)
                acc[o] = fmaf(zz[j], wr[o], acc[o]);
        }
    }
    float* ob = out + (size_t)n*64;
    #pragma unroll
    for (int o = 0; o < 64; ++o) ob[o] = acc[o];
}

extern "C" void kernel_launch(void* const* d_in, const int* in_sizes, int n_in,
                              void* d_out, int out_size, void* d_ws, size_t ws_size,
                              hipStream_t stream) {
    const float* z    = (const float*)d_in[0];
    const int*   ei   = (const int*)d_in[1];
    const float* Wq   = (const float*)d_in[2];
    const float* Wqb  = (const float*)d_in[3];
    const float* Wk   = (const float*)d_in[4];
    const float* Wkb  = (const float*)d_in[5];
    const float* Wv   = (const float*)d_in[6];
    const float* Wvb  = (const float*)d_in[7];
    const float* Wo   = (const float*)d_in[8];
    const float* Wob  = (const float*)d_in[9];
    const float* brb  = (const float*)d_in[10];
    const float* proj = (const float*)d_in[11];
    const float* g    = (const float*)d_in[12];
    float* out = (float*)d_out;
    float* A   = out + (size_t)NN*64;
    float* ws  = (float*)d_ws;

    float* Wt      = ws;                 // 131072
    float* bext    = ws + 131072;        // 1024
    float* WoT     = ws + 132096;        // 16384
    float* kvs     = ws + 148480;        // 81920
    float* ktg     = ws + 230400;        // 1280
    float* kp_sum  = ws + 231680;        // 128
    unsigned* stab = (unsigned*)(ws + 231808); // 4
    int* din       = (int*)(ws + 231812);      // 50000
    int* dout_     = (int*)(ws + 281812);      // 50000
    float* vbuf    = ws + 331840;        // 12.8M
    float* qp      = ws + 13131840;      // 6.4M
    float* kpb     = ws + 19531840;      // 6.4M (raw dash; dead after k_kp)
    float* znext   = ws + 25931840;      // 12.8M
    int* offsets   = (int*)(ws + 38731840);    // 50001 (pad to 50004)
    int* cursor    = (int*)(ws + 38781844);    // 50000
    int* bsum      = (int*)(ws + 38831844);    // 196
    int* boff      = (int*)(ws + 38832040);    // 196
    float* rsd     = ws + 38832236;            // 50000 -> 38882236
    unsigned short* Wcb = (unsigned short*)(ws + 38882240);      // 262144 ushorts
    unsigned short* kvs_bfT = (unsigned short*)(ws + 39013312);  // 81920 ushorts -> end ~39054272
    // aliases:
    //   vT  (256 x 50176 bf16 = 25.7MB) -> znext region (dead until k_znext_mfma)
    //   csr_pack (800000 int2)          -> kpb region [0 .. 1600000)
    //   A_scratch (3.2M floats)         -> kpb region [1600000 .. 4800000)
    //   vr  (12.8M bf16)                -> qp region (fp32 qp dead after k_znext_mfma)
    //   kp_bf  (6.4M bf16)              -> A segment of d_out
    //   qpn_bf (6.4M bf16)              -> out segment of d_out
    unsigned short* vT     = (unsigned short*)znext;
    int2* csr_pack         = (int2*)kpb;
    float* A_scratch       = kpb + 1600000;
    unsigned short* vr     = (unsigned short*)qp;
    unsigned short* kp_bf  = (unsigned short*)A;
    unsigned short* qpn_bf = (unsigned short*)out;

    hipMemsetAsync(ws + 148480, 0, (size_t)(331840 - 148480)*sizeof(float), stream);
    k_prep<<<128, 256, 0, stream>>>(Wq, Wqb, Wk, Wkb, Wv, Wvb, Wo, proj, Wt, bext, WoT);
    k_prep2<<<512, 256, 0, stream>>>(Wt, Wcb);
    k_ztail<<<88, 256, 0, stream>>>((unsigned*)vT);
    k_qkv_mfma<<<391, 256, 0, stream>>>(z, Wcb, bext, vbuf, qp, kpb, stab);
    k_deg<<<3125, 256, 0, stream>>>(ei, din, dout_);
    k_scan_part<<<196, 256, 0, stream>>>(din, bsum);
    k_scan_top<<<1, 64, 0, stream>>>(bsum, boff);
    k_scan_fin<<<196, 256, 0, stream>>>(din, boff, offsets, cursor, dout_, rsd);
    k_kp<<<512, 256, 0, stream>>>(kpb, stab, kp_sum, kp_bf);      // raw kpb dead after this
    k_scatter<<<3125, 256, 0, stream>>>(ei, cursor, csr_pack);
    k_vt<<<dim3(782, 4), 256, 0, stream>>>(vbuf, vT);
    k_kvs<<<dim3(KVSNB, 4), 256, 0, stream>>>(kp_bf, g, vT, kvs, ktg);
    k_kvsbf<<<320, 256, 0, stream>>>(kvs, kvs_bfT);
    k_znext_mfma<<<dim3(782, 4), 256, 0, stream>>>(qp, kvs_bfT, ktg, kp_sum, znext, qpn_bf);
    k_vr<<<12500, 256, 0, stream>>>(vbuf, rsd, vr);                 // vr aliases qp (dead now)
    k_convedge<<<12500, 256, 0, stream>>>(offsets, csr_pack, din, vr, kp_bf,
                                          qpn_bf, brb, znext, A_scratch);
    k_out<<<196, 256, 0, stream>>>(znext, WoT, Wob, out);
    hipMemcpyAsync(A, A_scratch, (size_t)EE*4*sizeof(float), hipMemcpyDeviceToDevice, stream);
}